// Round 3
// baseline (494.093 us; speedup 1.0000x reference)
//
#include <hip/hip_runtime.h>
#include <math.h>

#define B 4
#define C 64
#define H 256
#define W 256
#define HW (H*W)            // 65536
#define CHW (C*HW)          // 4194304
#define BCHW (B*CHW)        // 16777216

typedef __attribute__((ext_vector_type(8))) short short8v;   // 8 bf16
typedef __attribute__((ext_vector_type(4))) float f32x4;

// ws layout (201.3 MB): qpk u32 [0,4B*BCHW), kpk u32, v bf16, vT bf16

__device__ inline uint32_t f32_to_bf16(float f) {
    uint32_t u = __float_as_uint(f);
    return (u + 0x7fffu + ((u >> 16) & 1u)) >> 16;   // RNE
}
__device__ inline float bf16_to_f32(uint32_t h) { return __uint_as_float(h << 16); }

__device__ inline void unpack8(uint4 a, uint4 b, short8v& hi, short8v& lo) {
    union { uint32_t u[4]; short8v v; } Hh, Ll;
    Hh.u[0] = (a.x & 0xffffu) | (a.y << 16);
    Hh.u[1] = (a.z & 0xffffu) | (a.w << 16);
    Hh.u[2] = (b.x & 0xffffu) | (b.y << 16);
    Hh.u[3] = (b.z & 0xffffu) | (b.w << 16);
    Ll.u[0] = (a.x >> 16) | (a.y & 0xffff0000u);
    Ll.u[1] = (a.z >> 16) | (a.w & 0xffff0000u);
    Ll.u[2] = (b.x >> 16) | (b.y & 0xffff0000u);
    Ll.u[3] = (b.z >> 16) | (b.w & 0xffff0000u);
    hi = Hh.v; lo = Ll.v;
}

// ---------------------------------------------------------------------------
// K1: qkv 1x1 conv. q,k packed hi/lo u32; v bf16.
// ---------------------------------------------------------------------------
__global__ __launch_bounds__(256) void qkv_kernel(
    const float* __restrict__ x, const float* __restrict__ w,
    const float* __restrict__ bias, uint32_t* __restrict__ qpk,
    uint32_t* __restrict__ kpk, ushort* __restrict__ vbf)
{
    __shared__ float wl[192 * 64];
    __shared__ float bl[192];
    int t = threadIdx.x;
    for (int i = t; i < 192 * 64; i += 256) wl[i] = w[i];
    if (t < 192) bl[t] = bias[t];
    __syncthreads();

    int p = blockIdx.x * 256 + t;
    int b = p >> 16;
    int s = p & (HW - 1);

    const float* xp = x + (size_t)b * CHW + s;
    float xr[64];
    #pragma unroll
    for (int c = 0; c < 64; ++c) xr[c] = xp[(size_t)c * HW];

    for (int oc = 0; oc < 192; ++oc) {
        float acc = bl[oc];
        const float* wrow = &wl[oc * 64];
        #pragma unroll
        for (int c = 0; c < 64; ++c) acc += wrow[c] * xr[c];
        int grp = oc >> 6, cc = oc & 63;
        size_t idx = ((size_t)(b * 64 + cc)) * HW + s;
        if (grp == 2) {
            vbf[idx] = (ushort)f32_to_bf16(acc);
        } else {
            uint32_t hb = f32_to_bf16(acc);
            uint32_t lb = f32_to_bf16(acc - bf16_to_f32(hb));
            (grp == 0 ? qpk : kpk)[idx] = hb | (lb << 16);
        }
    }
}

// ---------------------------------------------------------------------------
// K1.5: transpose v -> vT
// ---------------------------------------------------------------------------
__global__ __launch_bounds__(256) void vt_kernel(
    const ushort* __restrict__ vbf, ushort* __restrict__ vt)
{
    __shared__ ushort tile[64][65];
    int t = threadIdx.x;
    int bc = blockIdx.x >> 4;
    int tj = blockIdx.x & 15;
    int h0 = (tj >> 2) * 64, w0 = (tj & 3) * 64;
    const ushort* vb = vbf + (size_t)bc * HW;
    ushort* vo = vt + (size_t)bc * HW;
    #pragma unroll
    for (int i = 0; i < 16; ++i) {
        int idx = t + 256 * i;
        int r = idx >> 6, c = idx & 63;
        tile[r][c] = vb[(h0 + r) * 256 + w0 + c];
    }
    __syncthreads();
    #pragma unroll
    for (int i = 0; i < 16; ++i) {
        int idx = t + 256 * i;
        int r = idx >> 6, c = idx & 63;
        vo[(w0 + r) * 256 + h0 + c] = tile[c][r];
    }
}

// ---------------------------------------------------------------------------
// K2 (fused): S=QK^T (MFMA, into LDS) -> conv3x3 -> softmax -> PV (MFMA) + x
// Block: (bc, 64-row h-tile). 66 S rows incl. conv halo (5 MFMA h-frags).
// ---------------------------------------------------------------------------
#define SST 260                   // S row stride in floats (bank spread)
#define ATS 264                   // attn row stride in ushorts

__global__ __launch_bounds__(256) void fused_kernel(
    const uint32_t* __restrict__ qpk, const uint32_t* __restrict__ kpk,
    const ushort* __restrict__ vt,
    const float* __restrict__ wdw, const float* __restrict__ bdw,
    const float* __restrict__ x, float* __restrict__ out)
{
    __shared__ float sS[66 * SST];          // 68.6 KB; attn bf16 overlays later
    __shared__ float red[64][4];
    __shared__ float mxf[64];
    __shared__ float smf[64];

    int t = threadIdx.x;
    int lane = t & 63, wv = t >> 6;
    int l15 = lane & 15, l4 = lane >> 4;

    int bid = blockIdx.x;
    int swz = (bid & 7) * 128 + (bid >> 3);   // 4 h-tiles of one bc -> same XCD
    int bc = swz >> 2;
    int h0 = (swz & 3) * 64;
    int c = bc & 63;

    const uint32_t* qb = qpk + (size_t)bc * HW;
    const uint32_t* kb = kpk + (size_t)bc * HW;
    const ushort*  vb = vt  + (size_t)bc * HW;
    const float*   xb = x   + (size_t)bc * HW;
    float*         ob = out + (size_t)bc * HW;

    // ================= Phase 1: S = Q K^T into LDS =================
    // computed rows cr = 0..79 <-> global h = h0-1+cr ; store cr < 66
    {
        int g0 = wv * 64;
        f32x4 acc[5][4];
        #pragma unroll
        for (int i = 0; i < 5; ++i)
            #pragma unroll
            for (int j = 0; j < 4; ++j) acc[i][j] = (f32x4)0.f;

        for (int kc = 0; kc < 8; ++kc) {
            int ko = kc * 32 + l4 * 8;
            short8v bhi[4], blo[4];
            #pragma unroll
            for (int gf = 0; gf < 4; ++gf) {
                const uint32_t* p = &kb[(g0 + gf * 16 + l15) * 256 + ko];
                uint4 u0 = *(const uint4*)p;
                uint4 u1 = *(const uint4*)(p + 4);
                unpack8(u0, u1, bhi[gf], blo[gf]);
            }
            #pragma unroll
            for (int hf = 0; hf < 5; ++hf) {
                int hq = h0 - 1 + hf * 16 + l15;
                hq = max(0, min(255, hq));       // clamp; conv zeroes invalid rows
                const uint32_t* p = &qb[hq * 256 + ko];
                uint4 u0 = *(const uint4*)p;
                uint4 u1 = *(const uint4*)(p + 4);
                short8v ahi, alo;
                unpack8(u0, u1, ahi, alo);
                #pragma unroll
                for (int gf = 0; gf < 4; ++gf) {
                    acc[hf][gf] = __builtin_amdgcn_mfma_f32_16x16x32_bf16(ahi, bhi[gf], acc[hf][gf], 0, 0, 0);
                    acc[hf][gf] = __builtin_amdgcn_mfma_f32_16x16x32_bf16(ahi, blo[gf], acc[hf][gf], 0, 0, 0);
                    acc[hf][gf] = __builtin_amdgcn_mfma_f32_16x16x32_bf16(alo, bhi[gf], acc[hf][gf], 0, 0, 0);
                }
            }
        }
        #pragma unroll
        for (int hf = 0; hf < 5; ++hf)
            #pragma unroll
            for (int gf = 0; gf < 4; ++gf)
                #pragma unroll
                for (int r = 0; r < 4; ++r) {
                    int cr = hf * 16 + l4 * 4 + r;
                    if (cr < 66)
                        sS[cr * SST + g0 + gf * 16 + l15] = acc[hf][gf][r];
                }
    }
    __syncthreads();

    // ================= Phase 2: conv3x3 (LDS rolling window) =================
    float w00 = wdw[c*9+0], w01 = wdw[c*9+1], w02 = wdw[c*9+2];
    float w10 = wdw[c*9+3], w11 = wdw[c*9+4], w12 = wdw[c*9+5];
    float w20 = wdw[c*9+6], w21 = wdw[c*9+7], w22 = wdw[c*9+8];
    float bias = bdw[c];

    float y[64];
    {
        float l0, m0, r0, l1, m1, r1;
        if (h0 > 0) {   // slot 0 = row h0-1
            m0 = sS[0 * SST + t];
            l0 = (t > 0)   ? sS[0 * SST + t - 1] : 0.f;
            r0 = (t < 255) ? sS[0 * SST + t + 1] : 0.f;
        } else { l0 = m0 = r0 = 0.f; }
        m1 = sS[1 * SST + t];
        l1 = (t > 0)   ? sS[1 * SST + t - 1] : 0.f;
        r1 = (t < 255) ? sS[1 * SST + t + 1] : 0.f;

        #pragma unroll
        for (int i = 0; i < 64; ++i) {
            float l2, m2, r2;
            if (h0 + 1 + i < 256) {     // slot i+2 = row h0+1+i
                m2 = sS[(i + 2) * SST + t];
                l2 = (t > 0)   ? sS[(i + 2) * SST + t - 1] : 0.f;
                r2 = (t < 255) ? sS[(i + 2) * SST + t + 1] : 0.f;
            } else { l2 = m2 = r2 = 0.f; }
            y[i] = bias
                 + w00*l0 + w01*m0 + w02*r0
                 + w10*l1 + w11*m1 + w12*r1
                 + w20*l2 + w21*m2 + w22*r2;
            l0 = l1; m0 = m1; r0 = r1;
            l1 = l2; m1 = m2; r1 = r2;
        }
    }

    // ================= Phase 3: softmax =================
    #pragma unroll
    for (int i = 0; i < 64; ++i) {
        float m = y[i];
        #pragma unroll
        for (int o = 32; o > 0; o >>= 1) m = fmaxf(m, __shfl_xor(m, o));
        if (lane == 0) red[i][wv] = m;
    }
    __syncthreads();                      // also: all conv reads of sS done
    if (t < 64) {
        float4 r4 = *(const float4*)red[t];
        mxf[t] = fmaxf(fmaxf(r4.x, r4.y), fmaxf(r4.z, r4.w));
    }
    __syncthreads();

    ushort* attnb = (ushort*)sS;          // overlay (sS dead now)
    #pragma unroll
    for (int i = 0; i < 64; ++i) {
        float e = __expf(y[i] - mxf[i]);
        attnb[i * ATS + t] = (ushort)f32_to_bf16(e);
        #pragma unroll
        for (int o = 32; o > 0; o >>= 1) e += __shfl_xor(e, o);
        if (lane == 0) red[i][wv] = e;
    }
    __syncthreads();
    if (t < 64) {
        float4 r4 = *(const float4*)red[t];
        smf[t] = 1.0f / ((r4.x + r4.y) + (r4.z + r4.w));
    }
    __syncthreads();

    // ================= Phase 4: PV via MFMA + residual =================
    {
        int w0 = wv * 64;
        f32x4 acc[4][4];
        #pragma unroll
        for (int i = 0; i < 4; ++i)
            #pragma unroll
            for (int j = 0; j < 4; ++j) acc[i][j] = (f32x4)0.f;

        for (int kc = 0; kc < 8; ++kc) {
            short8v bfr[4];
            #pragma unroll
            for (int wf = 0; wf < 4; ++wf) {
                const ushort* p = vb + (size_t)(w0 + wf * 16 + l15) * 256 + kc * 32 + l4 * 8;
                bfr[wf] = *(const short8v*)p;
            }
            #pragma unroll
            for (int hf = 0; hf < 4; ++hf) {
                short8v afr = *(const short8v*)&attnb[(hf * 16 + l15) * ATS + kc * 32 + l4 * 8];
                #pragma unroll
                for (int wf = 0; wf < 4; ++wf)
                    acc[hf][wf] = __builtin_amdgcn_mfma_f32_16x16x32_bf16(afr, bfr[wf], acc[hf][wf], 0, 0, 0);
            }
        }

        #pragma unroll
        for (int hf = 0; hf < 4; ++hf)
            #pragma unroll
            for (int r = 0; r < 4; ++r) {
                int row = hf * 16 + l4 * 4 + r;
                float inv = smf[row];
                int hg = h0 + row;
                #pragma unroll
                for (int wf = 0; wf < 4; ++wf) {
                    int wc = w0 + wf * 16 + l15;
                    ob[hg * 256 + wc] = acc[hf][wf][r] * inv + xb[hg * 256 + wc];
                }
            }
    }
}

// ---------------------------------------------------------------------------
extern "C" void kernel_launch(void* const* d_in, const int* in_sizes, int n_in,
                              void* d_out, int out_size, void* d_ws, size_t ws_size,
                              hipStream_t stream)
{
    const float* x     = (const float*)d_in[0];
    const float* w_qkv = (const float*)d_in[1];
    const float* b_qkv = (const float*)d_in[2];
    const float* w_dw  = (const float*)d_in[3];
    const float* b_dw  = (const float*)d_in[4];

    uint32_t* qpk = (uint32_t*)d_ws;
    uint32_t* kpk = qpk + (size_t)BCHW;
    ushort*   vbf = (ushort*)(qpk + (size_t)2 * BCHW);
    ushort*   vtp = vbf + (size_t)BCHW;
    float*    out = (float*)d_out;

    qkv_kernel  <<<B * HW / 256, 256, 0, stream>>>(x, w_qkv, b_qkv, qpk, kpk, vbf);
    vt_kernel   <<<B * C * 16,   256, 0, stream>>>(vbf, vtp);
    fused_kernel<<<B * C * 4,    256, 0, stream>>>(qpk, kpk, vtp, w_dw, b_dw, x, out);
}

// Round 4
// 361.533 us; speedup vs baseline: 1.3667x; 1.3667x over previous
//
#include <hip/hip_runtime.h>
#include <math.h>

#define B 4
#define C 64
#define H 256
#define W 256
#define HW (H*W)            // 65536
#define CHW (C*HW)          // 4194304
#define BCHW (B*CHW)        // 16777216

typedef __attribute__((ext_vector_type(8))) short short8v;   // 8 bf16
typedef __attribute__((ext_vector_type(4))) float f32x4;

// ws layout: 6 ushort planes of BCHW each (total 201.3 MB):
//   qhi, qlo, khi, klo, v, vT

__device__ inline uint32_t f32_to_bf16(float f) {
    uint32_t u = __float_as_uint(f);
    return (u + 0x7fffu + ((u >> 16) & 1u)) >> 16;   // RNE
}
__device__ inline float bf16_to_f32(uint32_t h) { return __uint_as_float(h << 16); }

// ---------------------------------------------------------------------------
// K1: qkv 1x1 conv. q,k -> hi/lo bf16 planes; v -> bf16.
// ---------------------------------------------------------------------------
__global__ __launch_bounds__(256) void qkv_kernel(
    const float* __restrict__ x, const float* __restrict__ w,
    const float* __restrict__ bias,
    ushort* __restrict__ qhi, ushort* __restrict__ qlo,
    ushort* __restrict__ khi, ushort* __restrict__ klo,
    ushort* __restrict__ vbf)
{
    __shared__ float wl[192 * 64];
    __shared__ float bl[192];
    int t = threadIdx.x;
    for (int i = t; i < 192 * 64; i += 256) wl[i] = w[i];
    if (t < 192) bl[t] = bias[t];
    __syncthreads();

    int p = blockIdx.x * 256 + t;
    int b = p >> 16;
    int s = p & (HW - 1);

    const float* xp = x + (size_t)b * CHW + s;
    float4 xr4[16];
    #pragma unroll
    for (int c4 = 0; c4 < 16; ++c4) {
        xr4[c4].x = xp[(size_t)(c4 * 4 + 0) * HW];
        xr4[c4].y = xp[(size_t)(c4 * 4 + 1) * HW];
        xr4[c4].z = xp[(size_t)(c4 * 4 + 2) * HW];
        xr4[c4].w = xp[(size_t)(c4 * 4 + 3) * HW];
    }

    #pragma unroll 2
    for (int oc = 0; oc < 192; ++oc) {
        const float4* wr = (const float4*)&wl[oc * 64];
        float a0 = bl[oc], a1 = 0.f, a2 = 0.f, a3 = 0.f;
        #pragma unroll
        for (int c4 = 0; c4 < 16; ++c4) {
            float4 wv4 = wr[c4], xv4 = xr4[c4];
            a0 = fmaf(wv4.x, xv4.x, a0);
            a1 = fmaf(wv4.y, xv4.y, a1);
            a2 = fmaf(wv4.z, xv4.z, a2);
            a3 = fmaf(wv4.w, xv4.w, a3);
        }
        float acc = (a0 + a1) + (a2 + a3);
        int grp = oc >> 6, cc = oc & 63;
        size_t idx = ((size_t)(b * 64 + cc)) * HW + s;
        if (grp == 2) {
            vbf[idx] = (ushort)f32_to_bf16(acc);
        } else {
            uint32_t hb = f32_to_bf16(acc);
            uint32_t lb = f32_to_bf16(acc - bf16_to_f32(hb));
            if (grp == 0) { qhi[idx] = (ushort)hb; qlo[idx] = (ushort)lb; }
            else          { khi[idx] = (ushort)hb; klo[idx] = (ushort)lb; }
        }
    }
}

// ---------------------------------------------------------------------------
// K1.5: transpose v -> vT
// ---------------------------------------------------------------------------
__global__ __launch_bounds__(256) void vt_kernel(
    const ushort* __restrict__ vbf, ushort* __restrict__ vt)
{
    __shared__ ushort tile[64][65];
    int t = threadIdx.x;
    int bc = blockIdx.x >> 4;
    int tj = blockIdx.x & 15;
    int h0 = (tj >> 2) * 64, w0 = (tj & 3) * 64;
    const ushort* vb = vbf + (size_t)bc * HW;
    ushort* vo = vt + (size_t)bc * HW;
    #pragma unroll
    for (int i = 0; i < 16; ++i) {
        int idx = t + 256 * i;
        int r = idx >> 6, c = idx & 63;
        tile[r][c] = vb[(h0 + r) * 256 + w0 + c];
    }
    __syncthreads();
    #pragma unroll
    for (int i = 0; i < 16; ++i) {
        int idx = t + 256 * i;
        int r = idx >> 6, c = idx & 63;
        vo[(w0 + r) * 256 + h0 + c] = tile[c][r];
    }
}

// ---------------------------------------------------------------------------
// K2 (fused, 512 thr / 8 waves): S=QK^T (MFMA->LDS) -> conv3x3 -> softmax
//                                 -> PV (MFMA) + residual
// Block: (bc, 64-row h-tile); 66 S rows incl. halo.
// ---------------------------------------------------------------------------
#define SST 260                   // S row stride (floats)
#define ATS 264                   // attn row stride (ushorts)

__global__ __launch_bounds__(512, 4) void fused_kernel(
    const ushort* __restrict__ qhi, const ushort* __restrict__ qlo,
    const ushort* __restrict__ khi, const ushort* __restrict__ klo,
    const ushort* __restrict__ vt,
    const float* __restrict__ wdw, const float* __restrict__ bdw,
    const float* __restrict__ x, float* __restrict__ out)
{
    __shared__ float sS[66 * SST];          // 68.6 KB; attn bf16 overlays later
    __shared__ float red[64][4];
    __shared__ float mxf[64];
    __shared__ float smf[64];

    int t = threadIdx.x;
    int lane = t & 63, wv = t >> 6;         // 8 waves
    int l15 = lane & 15, l4 = lane >> 4;
    int col = t & 255, half = t >> 8;       // conv/softmax: 2 halves x 256 cols
    int wg4 = wv & 3;                       // wave within half
    int base = half * 32;

    int bid = blockIdx.x;
    int swz = (bid & 7) * 128 + (bid >> 3); // 4 h-tiles of one bc -> same XCD
    int bc = swz >> 2;
    int h0 = (swz & 3) * 64;
    int c = bc & 63;

    const ushort* qhb = qhi + (size_t)bc * HW;
    const ushort* qlb = qlo + (size_t)bc * HW;
    const ushort* khb = khi + (size_t)bc * HW;
    const ushort* klb = klo + (size_t)bc * HW;
    const ushort* vb  = vt  + (size_t)bc * HW;
    const float*  xb  = x   + (size_t)bc * HW;
    float*        ob  = out + (size_t)bc * HW;

    float w00 = wdw[c*9+0], w01 = wdw[c*9+1], w02 = wdw[c*9+2];
    float w10 = wdw[c*9+3], w11 = wdw[c*9+4], w12 = wdw[c*9+5];
    float w20 = wdw[c*9+6], w21 = wdw[c*9+7], w22 = wdw[c*9+8];
    float bias = bdw[c];

    // ================= Phase 1: S = Q K^T into LDS =================
    {
        int g0 = wv * 32;
        f32x4 acc[5][2];
        #pragma unroll
        for (int i = 0; i < 5; ++i)
            #pragma unroll
            for (int j = 0; j < 2; ++j) acc[i][j] = (f32x4)0.f;

        for (int kc = 0; kc < 8; ++kc) {
            int ko = kc * 32 + l4 * 8;
            short8v bh[2], bl_[2];
            #pragma unroll
            for (int gf = 0; gf < 2; ++gf) {
                int go = (g0 + gf * 16 + l15) * 256 + ko;
                bh[gf]  = *(const short8v*)&khb[go];
                bl_[gf] = *(const short8v*)&klb[go];
            }
            #pragma unroll
            for (int hf = 0; hf < 5; ++hf) {
                int hq = h0 - 1 + hf * 16 + l15;
                hq = max(0, min(255, hq));       // clamp; conv zeroes invalid rows
                int qo = hq * 256 + ko;
                short8v ah = *(const short8v*)&qhb[qo];
                short8v al = *(const short8v*)&qlb[qo];
                #pragma unroll
                for (int gf = 0; gf < 2; ++gf) {
                    acc[hf][gf] = __builtin_amdgcn_mfma_f32_16x16x32_bf16(ah, bh[gf],  acc[hf][gf], 0, 0, 0);
                    acc[hf][gf] = __builtin_amdgcn_mfma_f32_16x16x32_bf16(ah, bl_[gf], acc[hf][gf], 0, 0, 0);
                    acc[hf][gf] = __builtin_amdgcn_mfma_f32_16x16x32_bf16(al, bh[gf],  acc[hf][gf], 0, 0, 0);
                }
            }
        }
        #pragma unroll
        for (int hf = 0; hf < 5; ++hf)
            #pragma unroll
            for (int gf = 0; gf < 2; ++gf)
                #pragma unroll
                for (int r = 0; r < 4; ++r) {
                    int cr = hf * 16 + l4 * 4 + r;
                    if (cr < 66)
                        sS[cr * SST + g0 + gf * 16 + l15] = acc[hf][gf][r];
                }
    }
    __syncthreads();

    // ================= Phase 2: conv3x3 (LDS rolling window) =================
    float y[32];
    {
        float l0, m0, r0, l1, m1, r1;
        if (base == 0 && h0 == 0) { l0 = m0 = r0 = 0.f; }
        else {
            m0 = sS[base * SST + col];
            l0 = (col > 0)   ? sS[base * SST + col - 1] : 0.f;
            r0 = (col < 255) ? sS[base * SST + col + 1] : 0.f;
        }
        m1 = sS[(base + 1) * SST + col];
        l1 = (col > 0)   ? sS[(base + 1) * SST + col - 1] : 0.f;
        r1 = (col < 255) ? sS[(base + 1) * SST + col + 1] : 0.f;

        #pragma unroll
        for (int i = 0; i < 32; ++i) {
            float l2, m2, r2;
            if (h0 + base + i + 1 < 256) {
                int sl = (base + i + 2) * SST;
                m2 = sS[sl + col];
                l2 = (col > 0)   ? sS[sl + col - 1] : 0.f;
                r2 = (col < 255) ? sS[sl + col + 1] : 0.f;
            } else { l2 = m2 = r2 = 0.f; }
            y[i] = bias
                 + w00*l0 + w01*m0 + w02*r0
                 + w10*l1 + w11*m1 + w12*r1
                 + w20*l2 + w21*m2 + w22*r2;
            l0 = l1; m0 = m1; r0 = r1;
            l1 = l2; m1 = m2; r1 = r2;
        }
    }

    // ================= Phase 3: softmax =================
    #pragma unroll
    for (int i = 0; i < 32; ++i) {
        float m = y[i];
        #pragma unroll
        for (int o = 32; o > 0; o >>= 1) m = fmaxf(m, __shfl_xor(m, o));
        if (lane == 0) red[base + i][wg4] = m;
    }
    __syncthreads();                       // all conv reads of sS done too
    if (t < 64) {
        float4 r4 = *(const float4*)red[t];
        mxf[t] = fmaxf(fmaxf(r4.x, r4.y), fmaxf(r4.z, r4.w));
    }
    __syncthreads();

    ushort* attnb = (ushort*)sS;           // overlay (sS dead now)
    #pragma unroll
    for (int i = 0; i < 32; ++i) {
        float e = __expf(y[i] - mxf[base + i]);
        attnb[(base + i) * ATS + col] = (ushort)f32_to_bf16(e);
        #pragma unroll
        for (int o = 32; o > 0; o >>= 1) e += __shfl_xor(e, o);
        if (lane == 0) red[base + i][wg4] = e;
    }
    __syncthreads();
    if (t < 64) {
        float4 r4 = *(const float4*)red[t];
        smf[t] = 1.0f / ((r4.x + r4.y) + (r4.z + r4.w));
    }
    __syncthreads();

    // ================= Phase 4: PV via MFMA + residual =================
    {
        int w0 = wv * 32;
        f32x4 acc[4][2];
        #pragma unroll
        for (int i = 0; i < 4; ++i)
            #pragma unroll
            for (int j = 0; j < 2; ++j) acc[i][j] = (f32x4)0.f;

        for (int kc = 0; kc < 8; ++kc) {
            short8v bfr[2];
            #pragma unroll
            for (int wf = 0; wf < 2; ++wf)
                bfr[wf] = *(const short8v*)&vb[(size_t)(w0 + wf * 16 + l15) * 256 + kc * 32 + l4 * 8];
            #pragma unroll
            for (int hf = 0; hf < 4; ++hf) {
                short8v afr = *(const short8v*)&attnb[(hf * 16 + l15) * ATS + kc * 32 + l4 * 8];
                #pragma unroll
                for (int wf = 0; wf < 2; ++wf)
                    acc[hf][wf] = __builtin_amdgcn_mfma_f32_16x16x32_bf16(afr, bfr[wf], acc[hf][wf], 0, 0, 0);
            }
        }

        #pragma unroll
        for (int hf = 0; hf < 4; ++hf)
            #pragma unroll
            for (int r = 0; r < 4; ++r) {
                int row = hf * 16 + l4 * 4 + r;
                float inv = smf[row];
                int hg = h0 + row;
                #pragma unroll
                for (int wf = 0; wf < 2; ++wf) {
                    int wc = w0 + wf * 16 + l15;
                    ob[hg * 256 + wc] = acc[hf][wf][r] * inv + xb[hg * 256 + wc];
                }
            }
    }
}

// ---------------------------------------------------------------------------
extern "C" void kernel_launch(void* const* d_in, const int* in_sizes, int n_in,
                              void* d_out, int out_size, void* d_ws, size_t ws_size,
                              hipStream_t stream)
{
    const float* x     = (const float*)d_in[0];
    const float* w_qkv = (const float*)d_in[1];
    const float* b_qkv = (const float*)d_in[2];
    const float* w_dw  = (const float*)d_in[3];
    const float* b_dw  = (const float*)d_in[4];

    ushort* qhi = (ushort*)d_ws;
    ushort* qlo = qhi + (size_t)BCHW;
    ushort* khi = qlo + (size_t)BCHW;
    ushort* klo = khi + (size_t)BCHW;
    ushort* vbf = klo + (size_t)BCHW;
    ushort* vtp = vbf + (size_t)BCHW;
    float*  out = (float*)d_out;

    qkv_kernel  <<<B * HW / 256, 256, 0, stream>>>(x, w_qkv, b_qkv, qhi, qlo, khi, klo, vbf);
    vt_kernel   <<<B * C * 16,   256, 0, stream>>>(vbf, vtp);
    fused_kernel<<<B * C * 4,    512, 0, stream>>>(qhi, qlo, khi, klo, vtp, w_dw, b_dw, x, out);
}

// Round 5
// 244.876 us; speedup vs baseline: 2.0177x; 1.4764x over previous
//
#include <hip/hip_runtime.h>
#include <math.h>

#define B 4
#define C 64
#define H 256
#define W 256
#define HW (H*W)            // 65536
#define CHW (C*HW)          // 4194304
#define BCHW (B*CHW)        // 16777216

typedef _Float16 half8v __attribute__((ext_vector_type(8)));
typedef float f32x4 __attribute__((ext_vector_type(4)));

// ws layout: 4 ushort(f16) planes of BCHW each (134 MB): q, k, v, vT

__device__ inline ushort f16_bits(float f) {
    _Float16 h = (_Float16)f;
    return *(ushort*)&h;
}

// ---------------------------------------------------------------------------
// K1: qkv 1x1 conv as f16 MFMA GEMM: D[192 oc][256 px] = W[192][64] * X[64][px]
// Block = 256 contiguous pixels of one b; 4 waves, 64 px each.
// A-frag = W rows (from global, converted); B-frag = x columns via 8 strided
// coalesced loads (x is [c][px], exactly B[k][n]); no LDS.
// ---------------------------------------------------------------------------
__global__ __launch_bounds__(256, 4) void qkv_kernel(
    const float* __restrict__ x, const float* __restrict__ w,
    const float* __restrict__ bias, ushort* __restrict__ qkv)
{
    int t = threadIdx.x;
    int lane = t & 63, wv = t >> 6;
    int l15 = lane & 15, l4 = lane >> 4;
    int p0 = blockIdx.x * 256;
    int b = p0 >> 16;
    int pxw = (p0 & (HW - 1)) + wv * 64;

    const float* xb = x + (size_t)b * CHW;

    // B-frags (x): bfr[pf][kc], built once, reused for all oc chunks
    half8v bfr[4][2];
    #pragma unroll
    for (int pf = 0; pf < 4; ++pf)
        #pragma unroll
        for (int kc = 0; kc < 2; ++kc) {
            int k0 = kc * 32 + l4 * 8;
            int px = pxw + pf * 16 + l15;
            half8v hv;
            #pragma unroll
            for (int j = 0; j < 8; ++j)
                hv[j] = (_Float16)xb[(size_t)(k0 + j) * HW + px];
            bfr[pf][kc] = hv;
        }

    #pragma unroll 1
    for (int ch = 0; ch < 4; ++ch) {
        int ocb = ch * 48;

        half8v afr[3][2];
        #pragma unroll
        for (int nf = 0; nf < 3; ++nf)
            #pragma unroll
            for (int kc = 0; kc < 2; ++kc) {
                int oc = ocb + nf * 16 + l15;
                int k0 = kc * 32 + l4 * 8;
                const float4* wp = (const float4*)&w[oc * 64 + k0];
                float4 wa = wp[0], wb = wp[1];
                half8v a;
                a[0] = (_Float16)wa.x; a[1] = (_Float16)wa.y;
                a[2] = (_Float16)wa.z; a[3] = (_Float16)wa.w;
                a[4] = (_Float16)wb.x; a[5] = (_Float16)wb.y;
                a[6] = (_Float16)wb.z; a[7] = (_Float16)wb.w;
                afr[nf][kc] = a;
            }

        f32x4 acc[3][4];
        #pragma unroll
        for (int nf = 0; nf < 3; ++nf)
            #pragma unroll
            for (int pf = 0; pf < 4; ++pf) acc[nf][pf] = (f32x4)0.f;

        #pragma unroll
        for (int kc = 0; kc < 2; ++kc)
            #pragma unroll
            for (int nf = 0; nf < 3; ++nf)
                #pragma unroll
                for (int pf = 0; pf < 4; ++pf)
                    acc[nf][pf] = __builtin_amdgcn_mfma_f32_16x16x32_f16(
                        afr[nf][kc], bfr[pf][kc], acc[nf][pf], 0, 0, 0);

        // epilogue: D row = oc (l4*4+r within frag), col = px (l15)
        #pragma unroll
        for (int nf = 0; nf < 3; ++nf)
            #pragma unroll
            for (int r = 0; r < 4; ++r) {
                int oc = ocb + nf * 16 + l4 * 4 + r;
                float bv = bias[oc];
                ushort* dst = qkv + (size_t)(oc >> 6) * BCHW
                            + ((size_t)b * 64 + (oc & 63)) * HW + pxw;
                #pragma unroll
                for (int pf = 0; pf < 4; ++pf)
                    dst[pf * 16 + l15] = f16_bits(acc[nf][pf][r] + bv);
            }
    }
}

// ---------------------------------------------------------------------------
// K1.5: transpose v -> vT (f16)
// ---------------------------------------------------------------------------
__global__ __launch_bounds__(256) void vt_kernel(
    const ushort* __restrict__ vbf, ushort* __restrict__ vt)
{
    __shared__ ushort tile[64][65];
    int t = threadIdx.x;
    int bc = blockIdx.x >> 4;
    int tj = blockIdx.x & 15;
    int h0 = (tj >> 2) * 64, w0 = (tj & 3) * 64;
    const ushort* vb = vbf + (size_t)bc * HW;
    ushort* vo = vt + (size_t)bc * HW;
    #pragma unroll
    for (int i = 0; i < 16; ++i) {
        int idx = t + 256 * i;
        int r = idx >> 6, c = idx & 63;
        tile[r][c] = vb[(h0 + r) * 256 + w0 + c];
    }
    __syncthreads();
    #pragma unroll
    for (int i = 0; i < 16; ++i) {
        int idx = t + 256 * i;
        int r = idx >> 6, c = idx & 63;
        vo[(w0 + r) * 256 + h0 + c] = tile[c][r];
    }
}

// ---------------------------------------------------------------------------
// K2 (fused, 512 thr / 8 waves, 32-row h-tile): S=QK^T (f16 MFMA -> LDS f32)
//   -> conv3x3 -> softmax -> PV (f16 MFMA) + residual
// LDS ~36 KB -> 4 blocks/CU.
// ---------------------------------------------------------------------------
#define SST 260                   // S row stride (floats)
#define ATS 264                   // attn row stride (f16)

__global__ __launch_bounds__(512, 8) void fused_kernel(
    const ushort* __restrict__ qf, const ushort* __restrict__ kf,
    const ushort* __restrict__ vtf,
    const float* __restrict__ wdw, const float* __restrict__ bdw,
    const float* __restrict__ x, float* __restrict__ out)
{
    __shared__ float sS[34 * SST];          // 35.4 KB; f16 attn overlays later
    __shared__ float red[32][4];
    __shared__ float mxf[32];
    __shared__ float smf[32];

    int t = threadIdx.x;
    int lane = t & 63, wv = t >> 6;         // 8 waves
    int l15 = lane & 15, l4 = lane >> 4;
    int col = t & 255, half = t >> 8;       // conv/softmax: 2 halves x 256 cols
    int wg4 = wv & 3;
    int base = half * 16;

    int bid = blockIdx.x;
    int swz = (bid & 7) * 256 + (bid >> 3); // 8 h-tiles of one bc -> same XCD
    int bc = swz >> 3;
    int h0 = (swz & 7) * 32;
    int c = bc & 63;

    const ushort* qb = qf  + (size_t)bc * HW;
    const ushort* kb = kf  + (size_t)bc * HW;
    const ushort* vb = vtf + (size_t)bc * HW;
    const float*  xb = x   + (size_t)bc * HW;
    float*        ob = out + (size_t)bc * HW;

    // ================= Phase 1: S = Q K^T into LDS =================
    // rows cr = 0..47 <-> h = h0-1+cr ; store cr < 34
    {
        int g0 = wv * 32;
        f32x4 acc[3][2];
        #pragma unroll
        for (int i = 0; i < 3; ++i)
            #pragma unroll
            for (int j = 0; j < 2; ++j) acc[i][j] = (f32x4)0.f;

        for (int kc = 0; kc < 8; ++kc) {
            int ko = kc * 32 + l4 * 8;
            half8v bh[2];
            #pragma unroll
            for (int gf = 0; gf < 2; ++gf)
                bh[gf] = *(const half8v*)&kb[(g0 + gf * 16 + l15) * 256 + ko];
            #pragma unroll
            for (int hf = 0; hf < 3; ++hf) {
                int hq = h0 - 1 + hf * 16 + l15;
                hq = max(0, min(255, hq));       // clamp; conv zeroes edges
                half8v ah = *(const half8v*)&qb[hq * 256 + ko];
                #pragma unroll
                for (int gf = 0; gf < 2; ++gf)
                    acc[hf][gf] = __builtin_amdgcn_mfma_f32_16x16x32_f16(
                        ah, bh[gf], acc[hf][gf], 0, 0, 0);
            }
        }
        #pragma unroll
        for (int hf = 0; hf < 3; ++hf)
            #pragma unroll
            for (int gf = 0; gf < 2; ++gf)
                #pragma unroll
                for (int r = 0; r < 4; ++r) {
                    int cr = hf * 16 + l4 * 4 + r;
                    if (cr < 34)
                        sS[cr * SST + g0 + gf * 16 + l15] = acc[hf][gf][r];
                }
    }
    __syncthreads();

    // ================= Phase 2: conv3x3 (LDS rolling window) =================
    float w00 = wdw[c*9+0], w01 = wdw[c*9+1], w02 = wdw[c*9+2];
    float w10 = wdw[c*9+3], w11 = wdw[c*9+4], w12 = wdw[c*9+5];
    float w20 = wdw[c*9+6], w21 = wdw[c*9+7], w22 = wdw[c*9+8];
    float bias = bdw[c];

    float y[16];
    {
        float l0, m0, r0, l1, m1, r1;
        if (base == 0 && h0 == 0) { l0 = m0 = r0 = 0.f; }
        else {
            m0 = sS[base * SST + col];
            l0 = (col > 0)   ? sS[base * SST + col - 1] : 0.f;
            r0 = (col < 255) ? sS[base * SST + col + 1] : 0.f;
        }
        m1 = sS[(base + 1) * SST + col];
        l1 = (col > 0)   ? sS[(base + 1) * SST + col - 1] : 0.f;
        r1 = (col < 255) ? sS[(base + 1) * SST + col + 1] : 0.f;

        #pragma unroll
        for (int i = 0; i < 16; ++i) {
            float l2, m2, r2;
            if (h0 + base + i + 1 < 256) {
                int sl = (base + i + 2) * SST;
                m2 = sS[sl + col];
                l2 = (col > 0)   ? sS[sl + col - 1] : 0.f;
                r2 = (col < 255) ? sS[sl + col + 1] : 0.f;
            } else { l2 = m2 = r2 = 0.f; }
            y[i] = bias
                 + w00*l0 + w01*m0 + w02*r0
                 + w10*l1 + w11*m1 + w12*r1
                 + w20*l2 + w21*m2 + w22*r2;
            l0 = l1; m0 = m1; r0 = r1;
            l1 = l2; m1 = m2; r1 = r2;
        }
    }

    // ================= Phase 3: softmax =================
    #pragma unroll
    for (int i = 0; i < 16; ++i) {
        float m = y[i];
        #pragma unroll
        for (int o = 32; o > 0; o >>= 1) m = fmaxf(m, __shfl_xor(m, o));
        if (lane == 0) red[base + i][wg4] = m;
    }
    __syncthreads();                       // all conv reads of sS done too
    if (t < 32) {
        float4 r4 = *(const float4*)red[t];
        mxf[t] = fmaxf(fmaxf(r4.x, r4.y), fmaxf(r4.z, r4.w));
    }
    __syncthreads();

    ushort* attnb = (ushort*)sS;           // overlay (sS dead now)
    #pragma unroll
    for (int i = 0; i < 16; ++i) {
        float e = __expf(y[i] - mxf[base + i]);
        attnb[(base + i) * ATS + col] = f16_bits(e);
        #pragma unroll
        for (int o = 32; o > 0; o >>= 1) e += __shfl_xor(e, o);
        if (lane == 0) red[base + i][wg4] = e;
    }
    __syncthreads();
    if (t < 32) {
        float4 r4 = *(const float4*)red[t];
        smf[t] = 1.0f / ((r4.x + r4.y) + (r4.z + r4.w));
    }
    __syncthreads();

    // ================= Phase 4: PV via MFMA + residual =================
    {
        int w0 = wv * 32;
        f32x4 acc[2][2];
        #pragma unroll
        for (int i = 0; i < 2; ++i)
            #pragma unroll
            for (int j = 0; j < 2; ++j) acc[i][j] = (f32x4)0.f;

        for (int kc = 0; kc < 8; ++kc) {
            half8v bfr[2];
            #pragma unroll
            for (int wf = 0; wf < 2; ++wf)
                bfr[wf] = *(const half8v*)&vb[(size_t)(w0 + wf * 16 + l15) * 256 + kc * 32 + l4 * 8];
            #pragma unroll
            for (int hf = 0; hf < 2; ++hf) {
                half8v afr = *(const half8v*)&attnb[(hf * 16 + l15) * ATS + kc * 32 + l4 * 8];
                #pragma unroll
                for (int wf = 0; wf < 2; ++wf)
                    acc[hf][wf] = __builtin_amdgcn_mfma_f32_16x16x32_f16(
                        afr, bfr[wf], acc[hf][wf], 0, 0, 0);
            }
        }

        #pragma unroll
        for (int hf = 0; hf < 2; ++hf)
            #pragma unroll
            for (int r = 0; r < 4; ++r) {
                int row = hf * 16 + l4 * 4 + r;
                float inv = smf[row];
                int hg = h0 + row;
                #pragma unroll
                for (int wf = 0; wf < 2; ++wf) {
                    int wc = w0 + wf * 16 + l15;
                    ob[hg * 256 + wc] = acc[hf][wf][r] * inv + xb[hg * 256 + wc];
                }
            }
    }
}

// ---------------------------------------------------------------------------
extern "C" void kernel_launch(void* const* d_in, const int* in_sizes, int n_in,
                              void* d_out, int out_size, void* d_ws, size_t ws_size,
                              hipStream_t stream)
{
    const float* x     = (const float*)d_in[0];
    const float* w_qkv = (const float*)d_in[1];
    const float* b_qkv = (const float*)d_in[2];
    const float* w_dw  = (const float*)d_in[3];
    const float* b_dw  = (const float*)d_in[4];

    ushort* qf  = (ushort*)d_ws;                 // q plane
    ushort* kf  = qf + (size_t)BCHW;             // k plane
    ushort* vf  = kf + (size_t)BCHW;             // v plane
    ushort* vtp = vf + (size_t)BCHW;             // vT plane
    float*  out = (float*)d_out;

    qkv_kernel  <<<B * HW / 256, 256, 0, stream>>>(x, w_qkv, b_qkv, qf);
    vt_kernel   <<<B * C * 16,   256, 0, stream>>>(vf, vtp);
    fused_kernel<<<B * C * 8,    512, 0, stream>>>(qf, kf, vtp, w_dw, b_dw, x, out);
}

// Round 6
// 235.111 us; speedup vs baseline: 2.1015x; 1.0415x over previous
//
#include <hip/hip_runtime.h>
#include <math.h>

#define B 4
#define C 64
#define H 256
#define W 256
#define HW (H*W)            // 65536
#define CHW (C*HW)          // 4194304
#define BCHW (B*CHW)        // 16777216

typedef _Float16 half8v __attribute__((ext_vector_type(8)));
typedef float f32x4 __attribute__((ext_vector_type(4)));

// ws layout: 4 ushort(f16) planes of BCHW each (134 MB): q, k, v, vT

__device__ inline ushort f16_bits(float f) {
    _Float16 h = (_Float16)f;
    return *(ushort*)&h;
}

// ---------------------------------------------------------------------------
// K1: qkv 1x1 conv as f16 MFMA GEMM: D[192 oc][256 px] = W[192][64] * X[64][px]
// Block = 256 contiguous pixels of one b; 4 waves, 64 px each.
// ---------------------------------------------------------------------------
__global__ __launch_bounds__(256, 4) void qkv_kernel(
    const float* __restrict__ x, const float* __restrict__ w,
    const float* __restrict__ bias, ushort* __restrict__ qkv)
{
    int t = threadIdx.x;
    int lane = t & 63, wv = t >> 6;
    int l15 = lane & 15, l4 = lane >> 4;
    int p0 = blockIdx.x * 256;
    int b = p0 >> 16;
    int pxw = (p0 & (HW - 1)) + wv * 64;

    const float* xb = x + (size_t)b * CHW;

    // B-frags (x): bfr[pf][kc], built once, reused for all oc chunks
    half8v bfr[4][2];
    #pragma unroll
    for (int pf = 0; pf < 4; ++pf)
        #pragma unroll
        for (int kc = 0; kc < 2; ++kc) {
            int k0 = kc * 32 + l4 * 8;
            int px = pxw + pf * 16 + l15;
            half8v hv;
            #pragma unroll
            for (int j = 0; j < 8; ++j)
                hv[j] = (_Float16)xb[(size_t)(k0 + j) * HW + px];
            bfr[pf][kc] = hv;
        }

    #pragma unroll 1
    for (int ch = 0; ch < 4; ++ch) {
        int ocb = ch * 48;

        half8v afr[3][2];
        #pragma unroll
        for (int nf = 0; nf < 3; ++nf)
            #pragma unroll
            for (int kc = 0; kc < 2; ++kc) {
                int oc = ocb + nf * 16 + l15;
                int k0 = kc * 32 + l4 * 8;
                const float4* wp = (const float4*)&w[oc * 64 + k0];
                float4 wa = wp[0], wb = wp[1];
                half8v a;
                a[0] = (_Float16)wa.x; a[1] = (_Float16)wa.y;
                a[2] = (_Float16)wa.z; a[3] = (_Float16)wa.w;
                a[4] = (_Float16)wb.x; a[5] = (_Float16)wb.y;
                a[6] = (_Float16)wb.z; a[7] = (_Float16)wb.w;
                afr[nf][kc] = a;
            }

        f32x4 acc[3][4];
        #pragma unroll
        for (int nf = 0; nf < 3; ++nf)
            #pragma unroll
            for (int pf = 0; pf < 4; ++pf) acc[nf][pf] = (f32x4)0.f;

        #pragma unroll
        for (int kc = 0; kc < 2; ++kc)
            #pragma unroll
            for (int nf = 0; nf < 3; ++nf)
                #pragma unroll
                for (int pf = 0; pf < 4; ++pf)
                    acc[nf][pf] = __builtin_amdgcn_mfma_f32_16x16x32_f16(
                        afr[nf][kc], bfr[pf][kc], acc[nf][pf], 0, 0, 0);

        // epilogue: D row = oc (l4*4+r within frag), col = px (l15)
        #pragma unroll
        for (int nf = 0; nf < 3; ++nf)
            #pragma unroll
            for (int r = 0; r < 4; ++r) {
                int oc = ocb + nf * 16 + l4 * 4 + r;
                float bv = bias[oc];
                ushort* dst = qkv + (size_t)(oc >> 6) * BCHW
                            + ((size_t)b * 64 + (oc & 63)) * HW + pxw;
                #pragma unroll
                for (int pf = 0; pf < 4; ++pf)
                    dst[pf * 16 + l15] = f16_bits(acc[nf][pf][r] + bv);
            }
    }
}

// ---------------------------------------------------------------------------
// K1.5: transpose v -> vT (f16)
// ---------------------------------------------------------------------------
__global__ __launch_bounds__(256) void vt_kernel(
    const ushort* __restrict__ vbf, ushort* __restrict__ vt)
{
    __shared__ ushort tile[64][65];
    int t = threadIdx.x;
    int bc = blockIdx.x >> 4;
    int tj = blockIdx.x & 15;
    int h0 = (tj >> 2) * 64, w0 = (tj & 3) * 64;
    const ushort* vb = vbf + (size_t)bc * HW;
    ushort* vo = vt + (size_t)bc * HW;
    #pragma unroll
    for (int i = 0; i < 16; ++i) {
        int idx = t + 256 * i;
        int r = idx >> 6, c = idx & 63;
        tile[r][c] = vb[(h0 + r) * 256 + w0 + c];
    }
    __syncthreads();
    #pragma unroll
    for (int i = 0; i < 16; ++i) {
        int idx = t + 256 * i;
        int r = idx >> 6, c = idx & 63;
        vo[(w0 + r) * 256 + h0 + c] = tile[c][r];
    }
}

// ---------------------------------------------------------------------------
// K2 (fused, 512 thr / 8 waves, 32-row h-tile): S=QK^T (f16 MFMA -> LDS f32)
//   -> conv3x3 -> softmax -> PV (f16 MFMA) + residual
// LDS ~37 KB, target 4 blocks/CU at ~64 VGPR (launch_bounds (512,4): no spills).
// ---------------------------------------------------------------------------
#define SST 264                   // S row stride (floats); 264%32==8 -> conflict-free acc store
#define ATS 264                   // attn row stride (f16)

__global__ __launch_bounds__(512, 4) void fused_kernel(
    const ushort* __restrict__ qf, const ushort* __restrict__ kf,
    const ushort* __restrict__ vtf,
    const float* __restrict__ wdw, const float* __restrict__ bdw,
    const float* __restrict__ x, float* __restrict__ out)
{
    __shared__ float sS[34 * SST];          // 35.9 KB; f16 attn overlays later
    __shared__ float red[32][4];
    __shared__ float mxf[32];
    __shared__ float smf[32];

    int t = threadIdx.x;
    int lane = t & 63, wv = t >> 6;         // 8 waves
    int l15 = lane & 15, l4 = lane >> 4;
    int col = t & 255, half = t >> 8;       // conv/softmax: 2 halves x 256 cols
    int wg4 = wv & 3;
    int base = half * 16;

    int bid = blockIdx.x;
    int swz = (bid & 7) * 256 + (bid >> 3); // 8 h-tiles of one bc -> same XCD
    int bc = swz >> 3;
    int h0 = (swz & 7) * 32;
    int c = bc & 63;

    const ushort* qb = qf  + (size_t)bc * HW;
    const ushort* kb = kf  + (size_t)bc * HW;
    const ushort* vb = vtf + (size_t)bc * HW;
    const float*  xb = x   + (size_t)bc * HW;
    float*        ob = out + (size_t)bc * HW;

    // ================= Phase 1: S = Q K^T into LDS =================
    // rows cr = 0..47 <-> h = h0-1+cr ; store cr < 34
    {
        int g0 = wv * 32;
        f32x4 acc[3][2];
        #pragma unroll
        for (int i = 0; i < 3; ++i)
            #pragma unroll
            for (int j = 0; j < 2; ++j) acc[i][j] = (f32x4)0.f;

        for (int kc = 0; kc < 8; ++kc) {
            int ko = kc * 32 + l4 * 8;
            half8v bh[2];
            #pragma unroll
            for (int gf = 0; gf < 2; ++gf)
                bh[gf] = *(const half8v*)&kb[(g0 + gf * 16 + l15) * 256 + ko];
            #pragma unroll
            for (int hf = 0; hf < 3; ++hf) {
                int hq = h0 - 1 + hf * 16 + l15;
                hq = max(0, min(255, hq));       // clamp; conv zeroes edges
                half8v ah = *(const half8v*)&qb[hq * 256 + ko];
                #pragma unroll
                for (int gf = 0; gf < 2; ++gf)
                    acc[hf][gf] = __builtin_amdgcn_mfma_f32_16x16x32_f16(
                        ah, bh[gf], acc[hf][gf], 0, 0, 0);
            }
        }
        #pragma unroll
        for (int hf = 0; hf < 3; ++hf)
            #pragma unroll
            for (int gf = 0; gf < 2; ++gf)
                #pragma unroll
                for (int r = 0; r < 4; ++r) {
                    int cr = hf * 16 + l4 * 4 + r;
                    if (cr < 34)
                        sS[cr * SST + g0 + gf * 16 + l15] = acc[hf][gf][r];
                }
    }
    __syncthreads();

    // ================= Phase 2: conv3x3 (LDS rolling window) =================
    float w00 = wdw[c*9+0], w01 = wdw[c*9+1], w02 = wdw[c*9+2];
    float w10 = wdw[c*9+3], w11 = wdw[c*9+4], w12 = wdw[c*9+5];
    float w20 = wdw[c*9+6], w21 = wdw[c*9+7], w22 = wdw[c*9+8];
    float bias = bdw[c];

    float y[16];
    {
        float l0, m0, r0, l1, m1, r1;
        if (base == 0 && h0 == 0) { l0 = m0 = r0 = 0.f; }
        else {
            m0 = sS[base * SST + col];
            l0 = (col > 0)   ? sS[base * SST + col - 1] : 0.f;
            r0 = (col < 255) ? sS[base * SST + col + 1] : 0.f;
        }
        m1 = sS[(base + 1) * SST + col];
        l1 = (col > 0)   ? sS[(base + 1) * SST + col - 1] : 0.f;
        r1 = (col < 255) ? sS[(base + 1) * SST + col + 1] : 0.f;

        #pragma unroll
        for (int i = 0; i < 16; ++i) {
            float l2, m2, r2;
            if (h0 + base + i + 1 < 256) {
                int sl = (base + i + 2) * SST;
                m2 = sS[sl + col];
                l2 = (col > 0)   ? sS[sl + col - 1] : 0.f;
                r2 = (col < 255) ? sS[sl + col + 1] : 0.f;
            } else { l2 = m2 = r2 = 0.f; }
            y[i] = bias
                 + w00*l0 + w01*m0 + w02*r0
                 + w10*l1 + w11*m1 + w12*r1
                 + w20*l2 + w21*m2 + w22*r2;
            l0 = l1; m0 = m1; r0 = r1;
            l1 = l2; m1 = m2; r1 = r2;
        }
    }

    // ================= Phase 3: softmax =================
    #pragma unroll
    for (int i = 0; i < 16; ++i) {
        float m = y[i];
        #pragma unroll
        for (int o = 32; o > 0; o >>= 1) m = fmaxf(m, __shfl_xor(m, o));
        if (lane == 0) red[base + i][wg4] = m;
    }
    __syncthreads();                       // all conv reads of sS done too
    if (t < 32) {
        float4 r4 = *(const float4*)red[t];
        mxf[t] = fmaxf(fmaxf(r4.x, r4.y), fmaxf(r4.z, r4.w));
    }
    __syncthreads();

    ushort* attnb = (ushort*)sS;           // overlay (sS dead now)
    #pragma unroll
    for (int i = 0; i < 16; ++i) {
        float e = __expf(y[i] - mxf[base + i]);
        attnb[(base + i) * ATS + col] = f16_bits(e);
        #pragma unroll
        for (int o = 32; o > 0; o >>= 1) e += __shfl_xor(e, o);
        if (lane == 0) red[base + i][wg4] = e;
    }
    __syncthreads();
    if (t < 32) {
        float4 r4 = *(const float4*)red[t];
        smf[t] = 1.0f / ((r4.x + r4.y) + (r4.z + r4.w));
    }
    __syncthreads();

    // ================= Phase 4: PV via MFMA + residual =================
    {
        int w0 = wv * 32;
        f32x4 acc[2][2];
        #pragma unroll
        for (int i = 0; i < 2; ++i)
            #pragma unroll
            for (int j = 0; j < 2; ++j) acc[i][j] = (f32x4)0.f;

        for (int kc = 0; kc < 8; ++kc) {
            half8v bfr[2];
            #pragma unroll
            for (int wf = 0; wf < 2; ++wf)
                bfr[wf] = *(const half8v*)&vb[(size_t)(w0 + wf * 16 + l15) * 256 + kc * 32 + l4 * 8];
            #pragma unroll
            for (int hf = 0; hf < 2; ++hf) {
                half8v afr = *(const half8v*)&attnb[(hf * 16 + l15) * ATS + kc * 32 + l4 * 8];
                #pragma unroll
                for (int wf = 0; wf < 2; ++wf)
                    acc[hf][wf] = __builtin_amdgcn_mfma_f32_16x16x32_f16(
                        afr, bfr[wf], acc[hf][wf], 0, 0, 0);
            }
        }

        #pragma unroll
        for (int hf = 0; hf < 2; ++hf)
            #pragma unroll
            for (int r = 0; r < 4; ++r) {
                int row = hf * 16 + l4 * 4 + r;
                float inv = smf[row];
                int hg = h0 + row;
                #pragma unroll
                for (int wf = 0; wf < 2; ++wf) {
                    int wc = w0 + wf * 16 + l15;
                    ob[hg * 256 + wc] = acc[hf][wf][r] * inv + xb[hg * 256 + wc];
                }
            }
    }
}

// ---------------------------------------------------------------------------
extern "C" void kernel_launch(void* const* d_in, const int* in_sizes, int n_in,
                              void* d_out, int out_size, void* d_ws, size_t ws_size,
                              hipStream_t stream)
{
    const float* x     = (const float*)d_in[0];
    const float* w_qkv = (const float*)d_in[1];
    const float* b_qkv = (const float*)d_in[2];
    const float* w_dw  = (const float*)d_in[3];
    const float* b_dw  = (const float*)d_in[4];

    ushort* qf  = (ushort*)d_ws;                 // q plane
    ushort* kf  = qf + (size_t)BCHW;             // k plane
    ushort* vf  = kf + (size_t)BCHW;             // v plane
    ushort* vtp = vf + (size_t)BCHW;             // vT plane
    float*  out = (float*)d_out;

    qkv_kernel  <<<B * HW / 256, 256, 0, stream>>>(x, w_qkv, b_qkv, qf);
    vt_kernel   <<<B * C * 16,   256, 0, stream>>>(vf, vtp);
    fused_kernel<<<B * C * 8,    512, 0, stream>>>(qf, kf, vtp, w_dw, b_dw, x, out);
}

// Round 9
// 178.498 us; speedup vs baseline: 2.7681x; 1.3172x over previous
//
#include <hip/hip_runtime.h>
#include <math.h>

#define B 4
#define C 64
#define H 256
#define W 256
#define HW (H*W)            // 65536
#define CHW (C*HW)          // 4194304
#define BCHW (B*CHW)        // 16777216

typedef _Float16 half8v __attribute__((ext_vector_type(8)));
typedef float f32x4 __attribute__((ext_vector_type(4)));

// ws layout: 4 ushort(f16) planes of BCHW each (134 MB): q, k, v, vT

__device__ inline ushort f16_bits(float f) {
    _Float16 h = (_Float16)f;
    return *(ushort*)&h;
}

// ---------------------------------------------------------------------------
// K1: qkv 1x1 conv as f16 MFMA GEMM: D[192 oc][256 px] = W[192][64] * X[64][px]
// Block = 256 contiguous pixels of one b; 4 waves, 64 px each.
// Epilogue: LDS repack -> coalesced 16B global stores.
// ---------------------------------------------------------------------------
__global__ __launch_bounds__(256, 4) void qkv_kernel(
    const float* __restrict__ x, const float* __restrict__ w,
    const float* __restrict__ bias, ushort* __restrict__ qkv)
{
    __shared__ ushort tile[48 * 264];      // 25.3 KB
    int t = threadIdx.x;
    int lane = t & 63, wv = t >> 6;
    int l15 = lane & 15, l4 = lane >> 4;
    int p0 = blockIdx.x * 256;
    int b = p0 >> 16;
    int ppx = p0 & (HW - 1);               // pixel offset WITHIN batch b
    int pxw = ppx + wv * 64;

    const float* xb = x + (size_t)b * CHW;

    // B-frags (x): bfr[pf][kc], built once, reused for all oc chunks
    half8v bfr[4][2];
    #pragma unroll
    for (int pf = 0; pf < 4; ++pf)
        #pragma unroll
        for (int kc = 0; kc < 2; ++kc) {
            int k0 = kc * 32 + l4 * 8;
            int px = pxw + pf * 16 + l15;
            half8v hv;
            #pragma unroll
            for (int j = 0; j < 8; ++j)
                hv[j] = (_Float16)xb[(size_t)(k0 + j) * HW + px];
            bfr[pf][kc] = hv;
        }

    #pragma unroll 1
    for (int ch = 0; ch < 4; ++ch) {
        int ocb = ch * 48;

        half8v afr[3][2];
        #pragma unroll
        for (int nf = 0; nf < 3; ++nf)
            #pragma unroll
            for (int kc = 0; kc < 2; ++kc) {
                int oc = ocb + nf * 16 + l15;
                int k0 = kc * 32 + l4 * 8;
                const float4* wp = (const float4*)&w[oc * 64 + k0];
                float4 wa = wp[0], wb = wp[1];
                half8v a;
                a[0] = (_Float16)wa.x; a[1] = (_Float16)wa.y;
                a[2] = (_Float16)wa.z; a[3] = (_Float16)wa.w;
                a[4] = (_Float16)wb.x; a[5] = (_Float16)wb.y;
                a[6] = (_Float16)wb.z; a[7] = (_Float16)wb.w;
                afr[nf][kc] = a;
            }

        f32x4 acc[3][4];
        #pragma unroll
        for (int nf = 0; nf < 3; ++nf)
            #pragma unroll
            for (int pf = 0; pf < 4; ++pf) acc[nf][pf] = (f32x4)0.f;

        #pragma unroll
        for (int kc = 0; kc < 2; ++kc)
            #pragma unroll
            for (int nf = 0; nf < 3; ++nf)
                #pragma unroll
                for (int pf = 0; pf < 4; ++pf)
                    acc[nf][pf] = __builtin_amdgcn_mfma_f32_16x16x32_f16(
                        afr[nf][kc], bfr[pf][kc], acc[nf][pf], 0, 0, 0);

        __syncthreads();                    // previous chunk's copy-out done
        #pragma unroll
        for (int nf = 0; nf < 3; ++nf)
            #pragma unroll
            for (int r = 0; r < 4; ++r) {
                int ocl = nf * 16 + l4 * 4 + r;
                float bv = bias[ocb + ocl];
                #pragma unroll
                for (int pf = 0; pf < 4; ++pf)
                    tile[ocl * 264 + wv * 64 + pf * 16 + l15] =
                        f16_bits(acc[nf][pf][r] + bv);
            }
        __syncthreads();

        // copy-out: 48 rows x 512 B = 1536 x 16 B chunks
        #pragma unroll
        for (int j = 0; j < 6; ++j) {
            int id = t + 256 * j;
            int row = id >> 5, seg = id & 31;
            uint4 val = *(const uint4*)&tile[row * 264 + seg * 8];
            int oc = ocb + row;
            ushort* dst = qkv + (size_t)(oc >> 6) * BCHW
                        + ((size_t)b * 64 + (oc & 63)) * HW + ppx + seg * 8;
            *(uint4*)dst = val;
        }
    }
}

// ---------------------------------------------------------------------------
// K1.5: transpose v -> vT (f16), ushort2 vectorized
// ---------------------------------------------------------------------------
__global__ __launch_bounds__(256) void vt_kernel(
    const ushort* __restrict__ vbf, ushort* __restrict__ vt)
{
    __shared__ ushort tile[64][66];
    int t = threadIdx.x;
    int bc = blockIdx.x >> 4;
    int tj = blockIdx.x & 15;
    int h0 = (tj >> 2) * 64, w0 = (tj & 3) * 64;
    const ushort* vb = vbf + (size_t)bc * HW;
    ushort* vo = vt + (size_t)bc * HW;
    #pragma unroll
    for (int i = 0; i < 8; ++i) {
        int id = t + 256 * i;
        int r = id >> 5, c2 = id & 31;
        *(uint*)&tile[r][c2 * 2] = *(const uint*)&vb[(h0 + r) * 256 + w0 + c2 * 2];
    }
    __syncthreads();
    #pragma unroll
    for (int i = 0; i < 8; ++i) {
        int id = t + 256 * i;
        int r = id >> 5, c2 = id & 31;
        uint val = (uint)tile[c2 * 2][r] | ((uint)tile[c2 * 2 + 1][r] << 16);
        *(uint*)&vo[(w0 + r) * 256 + h0 + c2 * 2] = val;
    }
}

// ---------------------------------------------------------------------------
// K2 (fused, 512 thr / 8 waves, 32-row h-tile):
//   S=QK^T (f16 MFMA -> LDS f32) -> conv3x3 -> max (LDS-transpose reduce)
//   -> exp -> PV + ones-column row sums (f16 MFMA) -> normalize + residual
// ---------------------------------------------------------------------------
#define SST 266                   // S row stride (floats)
#define YST 268                   // y scratch stride (floats)
#define ATS 264                   // attn row stride (f16)

__global__ __launch_bounds__(512, 4) void fused_kernel(
    const ushort* __restrict__ qf, const ushort* __restrict__ kf,
    const ushort* __restrict__ vtf,
    const float* __restrict__ wdw, const float* __restrict__ bdw,
    const float* __restrict__ x, float* __restrict__ out)
{
    __shared__ float sbuf[34 * SST];        // 36.2 KB; yL / f16 attn overlay
    __shared__ float mxf[32];

    int t = threadIdx.x;
    int lane = t & 63, wv = t >> 6;         // 8 waves
    int l15 = lane & 15, l4 = lane >> 4;
    int col = t & 255, half = t >> 8;       // conv/exp: 2 halves x 256 cols
    int base = half * 16;

    int bid = blockIdx.x;
    int swz = (bid & 7) * 256 + (bid >> 3); // 8 h-tiles of one bc -> same XCD
    int bc = swz >> 3;
    int h0 = (swz & 7) * 32;
    int c = bc & 63;

    const ushort* qb = qf  + (size_t)bc * HW;
    const ushort* kb = kf  + (size_t)bc * HW;
    const ushort* vb = vtf + (size_t)bc * HW;
    const float*  xb = x   + (size_t)bc * HW;
    float*        ob = out + (size_t)bc * HW;

    // ================= Phase 1: S = Q K^T into LDS =================
    // rows cr = 0..47 <-> h = h0-1+cr ; store cr < 34. K frags double-buffered.
    {
        int g0 = wv * 32;
        const ushort* kr0 = kb + (g0 + l15) * 256 + l4 * 8;
        const ushort* kr1 = kb + (g0 + 16 + l15) * 256 + l4 * 8;
        int hq0 = min(max(h0 - 1 + l15, 0), 255);
        int hq1 = min(max(h0 + 15 + l15, 0), 255);
        int hq2 = min(max(h0 + 31 + l15, 0), 255);
        const ushort* qr0 = qb + hq0 * 256 + l4 * 8;
        const ushort* qr1 = qb + hq1 * 256 + l4 * 8;
        const ushort* qr2 = qb + hq2 * 256 + l4 * 8;

        f32x4 acc[3][2];
        #pragma unroll
        for (int i = 0; i < 3; ++i)
            #pragma unroll
            for (int j = 0; j < 2; ++j) acc[i][j] = (f32x4)0.f;

        half8v ka[2][2];
        ka[0][0] = *(const half8v*)kr0;
        ka[0][1] = *(const half8v*)kr1;

        #pragma unroll
        for (int kc = 0; kc < 8; ++kc) {
            int cur = kc & 1, nxt = cur ^ 1;
            if (kc < 7) {
                ka[nxt][0] = *(const half8v*)(kr0 + (kc + 1) * 32);
                ka[nxt][1] = *(const half8v*)(kr1 + (kc + 1) * 32);
            }
            half8v a0 = *(const half8v*)(qr0 + kc * 32);
            half8v a1 = *(const half8v*)(qr1 + kc * 32);
            half8v a2 = *(const half8v*)(qr2 + kc * 32);
            __builtin_amdgcn_s_setprio(1);
            acc[0][0] = __builtin_amdgcn_mfma_f32_16x16x32_f16(a0, ka[cur][0], acc[0][0], 0, 0, 0);
            acc[0][1] = __builtin_amdgcn_mfma_f32_16x16x32_f16(a0, ka[cur][1], acc[0][1], 0, 0, 0);
            acc[1][0] = __builtin_amdgcn_mfma_f32_16x16x32_f16(a1, ka[cur][0], acc[1][0], 0, 0, 0);
            acc[1][1] = __builtin_amdgcn_mfma_f32_16x16x32_f16(a1, ka[cur][1], acc[1][1], 0, 0, 0);
            acc[2][0] = __builtin_amdgcn_mfma_f32_16x16x32_f16(a2, ka[cur][0], acc[2][0], 0, 0, 0);
            acc[2][1] = __builtin_amdgcn_mfma_f32_16x16x32_f16(a2, ka[cur][1], acc[2][1], 0, 0, 0);
            __builtin_amdgcn_s_setprio(0);
        }
        #pragma unroll
        for (int hf = 0; hf < 3; ++hf)
            #pragma unroll
            for (int gf = 0; gf < 2; ++gf)
                #pragma unroll
                for (int r = 0; r < 4; ++r) {
                    int cr = hf * 16 + l4 * 4 + r;
                    if (cr < 34)
                        sbuf[cr * SST + g0 + gf * 16 + l15] = acc[hf][gf][r];
                }
    }
    __syncthreads();

    // ================= Phase 2: conv3x3 (LDS rolling window) =================
    float w00 = wdw[c*9+0], w01 = wdw[c*9+1], w02 = wdw[c*9+2];
    float w10 = wdw[c*9+3], w11 = wdw[c*9+4], w12 = wdw[c*9+5];
    float w20 = wdw[c*9+6], w21 = wdw[c*9+7], w22 = wdw[c*9+8];
    float bias = bdw[c];

    float y[16];
    {
        float l0, m0, r0, l1, m1, r1;
        if (base == 0 && h0 == 0) { l0 = m0 = r0 = 0.f; }
        else {
            m0 = sbuf[base * SST + col];
            l0 = (col > 0)   ? sbuf[base * SST + col - 1] : 0.f;
            r0 = (col < 255) ? sbuf[base * SST + col + 1] : 0.f;
        }
        m1 = sbuf[(base + 1) * SST + col];
        l1 = (col > 0)   ? sbuf[(base + 1) * SST + col - 1] : 0.f;
        r1 = (col < 255) ? sbuf[(base + 1) * SST + col + 1] : 0.f;

        #pragma unroll
        for (int i = 0; i < 16; ++i) {
            float l2, m2, r2;
            if (h0 + base + i + 1 < 256) {
                int sl = (base + i + 2) * SST;
                m2 = sbuf[sl + col];
                l2 = (col > 0)   ? sbuf[sl + col - 1] : 0.f;
                r2 = (col < 255) ? sbuf[sl + col + 1] : 0.f;
            } else { l2 = m2 = r2 = 0.f; }
            y[i] = bias
                 + w00*l0 + w01*m0 + w02*r0
                 + w10*l1 + w11*m1 + w12*r1
                 + w20*l2 + w21*m2 + w22*r2;
            l0 = l1; m0 = m1; r0 = r1;
            l1 = l2; m1 = m2; r1 = r2;
        }
    }
    __syncthreads();                       // conv reads of sbuf done

    // ================= Phase 3a: row max via LDS transpose =================
    float* yL = sbuf;                      // stride YST, rows 0..31
    #pragma unroll
    for (int i = 0; i < 16; ++i)
        yL[(base + i) * YST + col] = y[i];
    __syncthreads();

    {
        int r = t >> 4, c16 = t & 15;      // 32 rows x 16 segments
        const f32x4* p = (const f32x4*)&yL[r * YST + c16 * 16];
        f32x4 v0 = p[0], v1 = p[1], v2 = p[2], v3 = p[3];
        float m = v0[0];
        #pragma unroll
        for (int j = 1; j < 4; ++j) m = fmaxf(m, v0[j]);
        #pragma unroll
        for (int j = 0; j < 4; ++j) m = fmaxf(m, v1[j]);
        #pragma unroll
        for (int j = 0; j < 4; ++j) m = fmaxf(m, v2[j]);
        #pragma unroll
        for (int j = 0; j < 4; ++j) m = fmaxf(m, v3[j]);
        m = fmaxf(m, __shfl_xor(m, 1));
        m = fmaxf(m, __shfl_xor(m, 2));
        m = fmaxf(m, __shfl_xor(m, 4));
        m = fmaxf(m, __shfl_xor(m, 8));
        if (c16 == 0) mxf[r] = m;
    }
    __syncthreads();

    // ================= Phase 3b: exp -> f16 attn =================
    ushort* attnb = (ushort*)sbuf;         // overlay (yL dead)
    #pragma unroll
    for (int i = 0; i < 16; ++i) {
        float e = __expf(y[i] - mxf[base + i]);
        attnb[(base + i) * ATS + col] = f16_bits(e);
    }
    __syncthreads();

    // ================= Phase 4: PV + ones-sum via MFMA, normalize + x ======
    {
        int w0 = wv * 32;
        const ushort* vr0 = vb + (size_t)(w0 + l15) * 256 + l4 * 8;
        const ushort* vr1 = vb + (size_t)(w0 + 16 + l15) * 256 + l4 * 8;

        half8v ones;
        #pragma unroll
        for (int j = 0; j < 8; ++j) ones[j] = (_Float16)1.0f;

        f32x4 acc[2][2], accs[2];
        #pragma unroll
        for (int i = 0; i < 2; ++i) {
            accs[i] = (f32x4)0.f;
            #pragma unroll
            for (int j = 0; j < 2; ++j) acc[i][j] = (f32x4)0.f;
        }

        half8v vfr[2][2];
        vfr[0][0] = *(const half8v*)vr0;
        vfr[0][1] = *(const half8v*)vr1;

        #pragma unroll
        for (int kc = 0; kc < 8; ++kc) {
            int cur = kc & 1, nxt = cur ^ 1;
            if (kc < 7) {
                vfr[nxt][0] = *(const half8v*)(vr0 + (kc + 1) * 32);
                vfr[nxt][1] = *(const half8v*)(vr1 + (kc + 1) * 32);
            }
            half8v af0 = *(const half8v*)&attnb[(l15) * ATS + kc * 32 + l4 * 8];
            half8v af1 = *(const half8v*)&attnb[(16 + l15) * ATS + kc * 32 + l4 * 8];
            __builtin_amdgcn_s_setprio(1);
            acc[0][0] = __builtin_amdgcn_mfma_f32_16x16x32_f16(af0, vfr[cur][0], acc[0][0], 0, 0, 0);
            acc[0][1] = __builtin_amdgcn_mfma_f32_16x16x32_f16(af0, vfr[cur][1], acc[0][1], 0, 0, 0);
            accs[0]   = __builtin_amdgcn_mfma_f32_16x16x32_f16(af0, ones, accs[0], 0, 0, 0);
            acc[1][0] = __builtin_amdgcn_mfma_f32_16x16x32_f16(af1, vfr[cur][0], acc[1][0], 0, 0, 0);
            acc[1][1] = __builtin_amdgcn_mfma_f32_16x16x32_f16(af1, vfr[cur][1], acc[1][1], 0, 0, 0);
            accs[1]   = __builtin_amdgcn_mfma_f32_16x16x32_f16(af1, ones, accs[1], 0, 0, 0);
            __builtin_amdgcn_s_setprio(0);
        }

        #pragma unroll
        for (int hf = 0; hf < 2; ++hf)
            #pragma unroll
            for (int r = 0; r < 4; ++r) {
                int row = hf * 16 + l4 * 4 + r;
                float inv = 1.0f / accs[hf][r];
                int hg = h0 + row;
                #pragma unroll
                for (int wf = 0; wf < 2; ++wf) {
                    int wc = w0 + wf * 16 + l15;
                    ob[hg * 256 + wc] = acc[hf][wf][r] * inv + xb[hg * 256 + wc];
                }
            }
    }
}

// ---------------------------------------------------------------------------
extern "C" void kernel_launch(void* const* d_in, const int* in_sizes, int n_in,
                              void* d_out, int out_size, void* d_ws, size_t ws_size,
                              hipStream_t stream)
{
    const float* x     = (const float*)d_in[0];
    const float* w_qkv = (const float*)d_in[1];
    const float* b_qkv = (const float*)d_in[2];
    const float* w_dw  = (const float*)d_in[3];
    const float* b_dw  = (const float*)d_in[4];

    ushort* qf  = (ushort*)d_ws;                 // q plane
    ushort* kf  = qf + (size_t)BCHW;             // k plane
    ushort* vf  = kf + (size_t)BCHW;             // v plane
    ushort* vtp = vf + (size_t)BCHW;             // vT plane
    float*  out = (float*)d_out;

    qkv_kernel  <<<B * HW / 256, 256, 0, stream>>>(x, w_qkv, b_qkv, qf);
    vt_kernel   <<<B * C * 16,   256, 0, stream>>>(vf, vtp);
    fused_kernel<<<B * C * 8,    512, 0, stream>>>(qf, kf, vtp, w_dw, b_dw, x, out);
}

// Round 10
// 178.297 us; speedup vs baseline: 2.7712x; 1.0011x over previous
//
#include <hip/hip_runtime.h>
#include <math.h>

#define B 4
#define C 64
#define H 256
#define W 256
#define HW (H*W)            // 65536
#define CHW (C*HW)          // 4194304
#define BCHW (B*CHW)        // 16777216

typedef _Float16 half8v __attribute__((ext_vector_type(8)));
typedef float f32x4 __attribute__((ext_vector_type(4)));

// ws layout: 4 ushort(f16) planes of BCHW each (134 MB): q, k, v, vT

__device__ inline ushort f16_bits(float f) {
    _Float16 h = (_Float16)f;
    return *(ushort*)&h;
}

// ---------------------------------------------------------------------------
// K1: qkv 1x1 conv as f16 MFMA GEMM: D[192 oc][256 px] = W[192][64] * X[64][px]
// Block = 256 contiguous pixels of one b; 4 waves, 64 px each.
// Epilogue: LDS repack -> coalesced 16B global stores.
// ---------------------------------------------------------------------------
__global__ __launch_bounds__(256, 4) void qkv_kernel(
    const float* __restrict__ x, const float* __restrict__ w,
    const float* __restrict__ bias, ushort* __restrict__ qkv)
{
    __shared__ ushort tile[48 * 264];      // 25.3 KB
    int t = threadIdx.x;
    int lane = t & 63, wv = t >> 6;
    int l15 = lane & 15, l4 = lane >> 4;
    int p0 = blockIdx.x * 256;
    int b = p0 >> 16;
    int ppx = p0 & (HW - 1);               // pixel offset WITHIN batch b
    int pxw = ppx + wv * 64;

    const float* xb = x + (size_t)b * CHW;

    // B-frags (x): bfr[pf][kc], built once, reused for all oc chunks
    half8v bfr[4][2];
    #pragma unroll
    for (int pf = 0; pf < 4; ++pf)
        #pragma unroll
        for (int kc = 0; kc < 2; ++kc) {
            int k0 = kc * 32 + l4 * 8;
            int px = pxw + pf * 16 + l15;
            half8v hv;
            #pragma unroll
            for (int j = 0; j < 8; ++j)
                hv[j] = (_Float16)xb[(size_t)(k0 + j) * HW + px];
            bfr[pf][kc] = hv;
        }

    #pragma unroll 1
    for (int ch = 0; ch < 4; ++ch) {
        int ocb = ch * 48;

        half8v afr[3][2];
        #pragma unroll
        for (int nf = 0; nf < 3; ++nf)
            #pragma unroll
            for (int kc = 0; kc < 2; ++kc) {
                int oc = ocb + nf * 16 + l15;
                int k0 = kc * 32 + l4 * 8;
                const float4* wp = (const float4*)&w[oc * 64 + k0];
                float4 wa = wp[0], wb = wp[1];
                half8v a;
                a[0] = (_Float16)wa.x; a[1] = (_Float16)wa.y;
                a[2] = (_Float16)wa.z; a[3] = (_Float16)wa.w;
                a[4] = (_Float16)wb.x; a[5] = (_Float16)wb.y;
                a[6] = (_Float16)wb.z; a[7] = (_Float16)wb.w;
                afr[nf][kc] = a;
            }

        f32x4 acc[3][4];
        #pragma unroll
        for (int nf = 0; nf < 3; ++nf)
            #pragma unroll
            for (int pf = 0; pf < 4; ++pf) acc[nf][pf] = (f32x4)0.f;

        #pragma unroll
        for (int kc = 0; kc < 2; ++kc)
            #pragma unroll
            for (int nf = 0; nf < 3; ++nf)
                #pragma unroll
                for (int pf = 0; pf < 4; ++pf)
                    acc[nf][pf] = __builtin_amdgcn_mfma_f32_16x16x32_f16(
                        afr[nf][kc], bfr[pf][kc], acc[nf][pf], 0, 0, 0);

        __syncthreads();                    // previous chunk's copy-out done
        #pragma unroll
        for (int nf = 0; nf < 3; ++nf)
            #pragma unroll
            for (int r = 0; r < 4; ++r) {
                int ocl = nf * 16 + l4 * 4 + r;
                float bv = bias[ocb + ocl];
                #pragma unroll
                for (int pf = 0; pf < 4; ++pf)
                    tile[ocl * 264 + wv * 64 + pf * 16 + l15] =
                        f16_bits(acc[nf][pf][r] + bv);
            }
        __syncthreads();

        // copy-out: 48 rows x 512 B = 1536 x 16 B chunks
        #pragma unroll
        for (int j = 0; j < 6; ++j) {
            int id = t + 256 * j;
            int row = id >> 5, seg = id & 31;
            uint4 val = *(const uint4*)&tile[row * 264 + seg * 8];
            int oc = ocb + row;
            ushort* dst = qkv + (size_t)(oc >> 6) * BCHW
                        + ((size_t)b * 64 + (oc & 63)) * HW + ppx + seg * 8;
            *(uint4*)dst = val;
        }
    }
}

// ---------------------------------------------------------------------------
// K1.5: transpose v -> vT (f16), ushort2 vectorized
// ---------------------------------------------------------------------------
__global__ __launch_bounds__(256) void vt_kernel(
    const ushort* __restrict__ vbf, ushort* __restrict__ vt)
{
    __shared__ ushort tile[64][66];
    int t = threadIdx.x;
    int bc = blockIdx.x >> 4;
    int tj = blockIdx.x & 15;
    int h0 = (tj >> 2) * 64, w0 = (tj & 3) * 64;
    const ushort* vb = vbf + (size_t)bc * HW;
    ushort* vo = vt + (size_t)bc * HW;
    #pragma unroll
    for (int i = 0; i < 8; ++i) {
        int id = t + 256 * i;
        int r = id >> 5, c2 = id & 31;
        *(uint*)&tile[r][c2 * 2] = *(const uint*)&vb[(h0 + r) * 256 + w0 + c2 * 2];
    }
    __syncthreads();
    #pragma unroll
    for (int i = 0; i < 8; ++i) {
        int id = t + 256 * i;
        int r = id >> 5, c2 = id & 31;
        uint val = (uint)tile[c2 * 2][r] | ((uint)tile[c2 * 2 + 1][r] << 16);
        *(uint*)&vo[(w0 + r) * 256 + h0 + c2 * 2] = val;
    }
}

// ---------------------------------------------------------------------------
// K2 (fused, 512 thr / 8 waves, 32-row h-tile):
//   S=QK^T (f16 MFMA -> LDS f32, Q+K double-buffered) -> conv3x3
//   -> max (LDS-transpose reduce) -> exp -> PV + ones-sum (V+attn dbuf)
//   -> normalize + residual
// ---------------------------------------------------------------------------
#define SST 266                   // S row stride (floats)
#define YST 268                   // y scratch stride (floats)
#define ATS 264                   // attn row stride (f16)

__global__ __launch_bounds__(512, 4) void fused_kernel(
    const ushort* __restrict__ qf, const ushort* __restrict__ kf,
    const ushort* __restrict__ vtf,
    const float* __restrict__ wdw, const float* __restrict__ bdw,
    const float* __restrict__ x, float* __restrict__ out)
{
    __shared__ float sbuf[34 * SST];        // 36.2 KB; yL / f16 attn overlay
    __shared__ float mxf[32];

    int t = threadIdx.x;
    int lane = t & 63, wv = t >> 6;         // 8 waves
    int l15 = lane & 15, l4 = lane >> 4;
    int col = t & 255, half = t >> 8;       // conv/exp: 2 halves x 256 cols
    int base = half * 16;

    int bid = blockIdx.x;
    int swz = (bid & 7) * 256 + (bid >> 3); // 8 h-tiles of one bc -> same XCD
    int bc = swz >> 3;
    int h0 = (swz & 7) * 32;
    int c = bc & 63;

    const ushort* qb = qf  + (size_t)bc * HW;
    const ushort* kb = kf  + (size_t)bc * HW;
    const ushort* vb = vtf + (size_t)bc * HW;
    const float*  xb = x   + (size_t)bc * HW;
    float*        ob = out + (size_t)bc * HW;

    // ================= Phase 1: S = Q K^T into LDS =================
    // rows cr = 0..47 <-> h = h0-1+cr ; store cr < 34. Q AND K double-buffered.
    {
        int g0 = wv * 32;
        const ushort* kr0 = kb + (g0 + l15) * 256 + l4 * 8;
        const ushort* kr1 = kb + (g0 + 16 + l15) * 256 + l4 * 8;
        int hq0 = min(max(h0 - 1 + l15, 0), 255);
        int hq1 = min(max(h0 + 15 + l15, 0), 255);
        int hq2 = min(max(h0 + 31 + l15, 0), 255);
        const ushort* qr0 = qb + hq0 * 256 + l4 * 8;
        const ushort* qr1 = qb + hq1 * 256 + l4 * 8;
        const ushort* qr2 = qb + hq2 * 256 + l4 * 8;

        f32x4 acc[3][2];
        #pragma unroll
        for (int i = 0; i < 3; ++i)
            #pragma unroll
            for (int j = 0; j < 2; ++j) acc[i][j] = (f32x4)0.f;

        half8v ka[2][2], qa[2][3];
        ka[0][0] = *(const half8v*)kr0;
        ka[0][1] = *(const half8v*)kr1;
        qa[0][0] = *(const half8v*)qr0;
        qa[0][1] = *(const half8v*)qr1;
        qa[0][2] = *(const half8v*)qr2;

        #pragma unroll
        for (int kc = 0; kc < 8; ++kc) {
            int cur = kc & 1, nxt = cur ^ 1;
            if (kc < 7) {
                ka[nxt][0] = *(const half8v*)(kr0 + (kc + 1) * 32);
                ka[nxt][1] = *(const half8v*)(kr1 + (kc + 1) * 32);
                qa[nxt][0] = *(const half8v*)(qr0 + (kc + 1) * 32);
                qa[nxt][1] = *(const half8v*)(qr1 + (kc + 1) * 32);
                qa[nxt][2] = *(const half8v*)(qr2 + (kc + 1) * 32);
            }
            __builtin_amdgcn_s_setprio(1);
            acc[0][0] = __builtin_amdgcn_mfma_f32_16x16x32_f16(qa[cur][0], ka[cur][0], acc[0][0], 0, 0, 0);
            acc[0][1] = __builtin_amdgcn_mfma_f32_16x16x32_f16(qa[cur][0], ka[cur][1], acc[0][1], 0, 0, 0);
            acc[1][0] = __builtin_amdgcn_mfma_f32_16x16x32_f16(qa[cur][1], ka[cur][0], acc[1][0], 0, 0, 0);
            acc[1][1] = __builtin_amdgcn_mfma_f32_16x16x32_f16(qa[cur][1], ka[cur][1], acc[1][1], 0, 0, 0);
            acc[2][0] = __builtin_amdgcn_mfma_f32_16x16x32_f16(qa[cur][2], ka[cur][0], acc[2][0], 0, 0, 0);
            acc[2][1] = __builtin_amdgcn_mfma_f32_16x16x32_f16(qa[cur][2], ka[cur][1], acc[2][1], 0, 0, 0);
            __builtin_amdgcn_s_setprio(0);
        }
        #pragma unroll
        for (int hf = 0; hf < 3; ++hf)
            #pragma unroll
            for (int gf = 0; gf < 2; ++gf)
                #pragma unroll
                for (int r = 0; r < 4; ++r) {
                    int cr = hf * 16 + l4 * 4 + r;
                    if (cr < 34)
                        sbuf[cr * SST + g0 + gf * 16 + l15] = acc[hf][gf][r];
                }
    }
    __syncthreads();

    // ---- early V primer issue: HBM latency hides under conv+max+exp ----
    int w0p = wv * 32;
    const ushort* vr0 = vb + (size_t)(w0p + l15) * 256 + l4 * 8;
    const ushort* vr1 = vb + (size_t)(w0p + 16 + l15) * 256 + l4 * 8;
    half8v vfr[2][2];
    vfr[0][0] = *(const half8v*)vr0;
    vfr[0][1] = *(const half8v*)vr1;

    // ================= Phase 2: conv3x3 (LDS rolling window) =================
    float w00 = wdw[c*9+0], w01 = wdw[c*9+1], w02 = wdw[c*9+2];
    float w10 = wdw[c*9+3], w11 = wdw[c*9+4], w12 = wdw[c*9+5];
    float w20 = wdw[c*9+6], w21 = wdw[c*9+7], w22 = wdw[c*9+8];
    float bias = bdw[c];

    float y[16];
    {
        float l0, m0, r0, l1, m1, r1;
        if (base == 0 && h0 == 0) { l0 = m0 = r0 = 0.f; }
        else {
            m0 = sbuf[base * SST + col];
            l0 = (col > 0)   ? sbuf[base * SST + col - 1] : 0.f;
            r0 = (col < 255) ? sbuf[base * SST + col + 1] : 0.f;
        }
        m1 = sbuf[(base + 1) * SST + col];
        l1 = (col > 0)   ? sbuf[(base + 1) * SST + col - 1] : 0.f;
        r1 = (col < 255) ? sbuf[(base + 1) * SST + col + 1] : 0.f;

        #pragma unroll
        for (int i = 0; i < 16; ++i) {
            float l2, m2, r2;
            if (h0 + base + i + 1 < 256) {
                int sl = (base + i + 2) * SST;
                m2 = sbuf[sl + col];
                l2 = (col > 0)   ? sbuf[sl + col - 1] : 0.f;
                r2 = (col < 255) ? sbuf[sl + col + 1] : 0.f;
            } else { l2 = m2 = r2 = 0.f; }
            y[i] = bias
                 + w00*l0 + w01*m0 + w02*r0
                 + w10*l1 + w11*m1 + w12*r1
                 + w20*l2 + w21*m2 + w22*r2;
            l0 = l1; m0 = m1; r0 = r1;
            l1 = l2; m1 = m2; r1 = r2;
        }
    }
    __syncthreads();                       // conv reads of sbuf done

    // ================= Phase 3a: row max via LDS transpose =================
    float* yL = sbuf;                      // stride YST, rows 0..31
    #pragma unroll
    for (int i = 0; i < 16; ++i)
        yL[(base + i) * YST + col] = y[i];
    __syncthreads();

    {
        int r = t >> 4, c16 = t & 15;      // 32 rows x 16 segments
        const f32x4* p = (const f32x4*)&yL[r * YST + c16 * 16];
        f32x4 v0 = p[0], v1 = p[1], v2 = p[2], v3 = p[3];
        float m = v0[0];
        #pragma unroll
        for (int j = 1; j < 4; ++j) m = fmaxf(m, v0[j]);
        #pragma unroll
        for (int j = 0; j < 4; ++j) m = fmaxf(m, v1[j]);
        #pragma unroll
        for (int j = 0; j < 4; ++j) m = fmaxf(m, v2[j]);
        #pragma unroll
        for (int j = 0; j < 4; ++j) m = fmaxf(m, v3[j]);
        m = fmaxf(m, __shfl_xor(m, 1));
        m = fmaxf(m, __shfl_xor(m, 2));
        m = fmaxf(m, __shfl_xor(m, 4));
        m = fmaxf(m, __shfl_xor(m, 8));
        if (c16 == 0) mxf[r] = m;
    }
    __syncthreads();

    // ================= Phase 3b: exp -> f16 attn =================
    ushort* attnb = (ushort*)sbuf;         // overlay (yL dead)
    #pragma unroll
    for (int i = 0; i < 16; ++i) {
        float e = __expf(y[i] - mxf[base + i]);
        attnb[(base + i) * ATS + col] = f16_bits(e);
    }
    __syncthreads();

    // ================= Phase 4: PV + ones-sum via MFMA, normalize + x ======
    {
        half8v ones;
        #pragma unroll
        for (int j = 0; j < 8; ++j) ones[j] = (_Float16)1.0f;

        f32x4 acc[2][2], accs[2];
        #pragma unroll
        for (int i = 0; i < 2; ++i) {
            accs[i] = (f32x4)0.f;
            #pragma unroll
            for (int j = 0; j < 2; ++j) acc[i][j] = (f32x4)0.f;
        }

        half8v af[2][2];
        af[0][0] = *(const half8v*)&attnb[l15 * ATS + l4 * 8];
        af[0][1] = *(const half8v*)&attnb[(16 + l15) * ATS + l4 * 8];

        #pragma unroll
        for (int kc = 0; kc < 8; ++kc) {
            int cur = kc & 1, nxt = cur ^ 1;
            if (kc < 7) {
                vfr[nxt][0] = *(const half8v*)(vr0 + (kc + 1) * 32);
                vfr[nxt][1] = *(const half8v*)(vr1 + (kc + 1) * 32);
                af[nxt][0] = *(const half8v*)&attnb[l15 * ATS + (kc + 1) * 32 + l4 * 8];
                af[nxt][1] = *(const half8v*)&attnb[(16 + l15) * ATS + (kc + 1) * 32 + l4 * 8];
            }
            __builtin_amdgcn_s_setprio(1);
            acc[0][0] = __builtin_amdgcn_mfma_f32_16x16x32_f16(af[cur][0], vfr[cur][0], acc[0][0], 0, 0, 0);
            acc[0][1] = __builtin_amdgcn_mfma_f32_16x16x32_f16(af[cur][0], vfr[cur][1], acc[0][1], 0, 0, 0);
            accs[0]   = __builtin_amdgcn_mfma_f32_16x16x32_f16(af[cur][0], ones, accs[0], 0, 0, 0);
            acc[1][0] = __builtin_amdgcn_mfma_f32_16x16x32_f16(af[cur][1], vfr[cur][0], acc[1][0], 0, 0, 0);
            acc[1][1] = __builtin_amdgcn_mfma_f32_16x16x32_f16(af[cur][1], vfr[cur][1], acc[1][1], 0, 0, 0);
            accs[1]   = __builtin_amdgcn_mfma_f32_16x16x32_f16(af[cur][1], ones, accs[1], 0, 0, 0);
            __builtin_amdgcn_s_setprio(0);
        }

        #pragma unroll
        for (int hf = 0; hf < 2; ++hf)
            #pragma unroll
            for (int r = 0; r < 4; ++r) {
                int row = hf * 16 + l4 * 4 + r;
                float inv = 1.0f / accs[hf][r];
                int hg = h0 + row;
                #pragma unroll
                for (int wf = 0; wf < 2; ++wf) {
                    int wc = w0p + wf * 16 + l15;
                    ob[hg * 256 + wc] = acc[hf][wf][r] * inv + xb[hg * 256 + wc];
                }
            }
    }
}

// ---------------------------------------------------------------------------
extern "C" void kernel_launch(void* const* d_in, const int* in_sizes, int n_in,
                              void* d_out, int out_size, void* d_ws, size_t ws_size,
                              hipStream_t stream)
{
    const float* x     = (const float*)d_in[0];
    const float* w_qkv = (const float*)d_in[1];
    const float* b_qkv = (const float*)d_in[2];
    const float* w_dw  = (const float*)d_in[3];
    const float* b_dw  = (const float*)d_in[4];

    ushort* qf  = (ushort*)d_ws;                 // q plane
    ushort* kf  = qf + (size_t)BCHW;             // k plane
    ushort* vf  = kf + (size_t)BCHW;             // v plane
    ushort* vtp = vf + (size_t)BCHW;             // vT plane
    float*  out = (float*)d_out;

    qkv_kernel  <<<B * HW / 256, 256, 0, stream>>>(x, w_qkv, b_qkv, qf);
    vt_kernel   <<<B * C * 16,   256, 0, stream>>>(vf, vtp);
    fused_kernel<<<B * C * 8,    512, 0, stream>>>(qf, kf, vtp, w_dw, b_dw, x, out);
}

// Round 11
// 132.377 us; speedup vs baseline: 3.7325x; 1.3469x over previous
//
#include <hip/hip_runtime.h>
#include <math.h>

#define B 4
#define C 64
#define H 256
#define W 256
#define HW (H*W)            // 65536
#define CHW (C*HW)          // 4194304
#define BCHW (B*CHW)        // 16777216

typedef _Float16 half8v __attribute__((ext_vector_type(8)));
typedef float f32x4 __attribute__((ext_vector_type(4)));

// ws layout: 4 ushort(f16) planes of BCHW each (134 MB): q, k, v, vT

__device__ inline ushort f16_bits(float f) {
    _Float16 h = (_Float16)f;
    return *(ushort*)&h;
}

// ---------------------------------------------------------------------------
// K1: qkv 1x1 conv as f16 MFMA GEMM (unchanged from round 9)
// ---------------------------------------------------------------------------
__global__ __launch_bounds__(256, 4) void qkv_kernel(
    const float* __restrict__ x, const float* __restrict__ w,
    const float* __restrict__ bias, ushort* __restrict__ qkv)
{
    __shared__ ushort tile[48 * 264];      // 25.3 KB
    int t = threadIdx.x;
    int lane = t & 63, wv = t >> 6;
    int l15 = lane & 15, l4 = lane >> 4;
    int p0 = blockIdx.x * 256;
    int b = p0 >> 16;
    int ppx = p0 & (HW - 1);               // pixel offset WITHIN batch b
    int pxw = ppx + wv * 64;

    const float* xb = x + (size_t)b * CHW;

    half8v bfr[4][2];
    #pragma unroll
    for (int pf = 0; pf < 4; ++pf)
        #pragma unroll
        for (int kc = 0; kc < 2; ++kc) {
            int k0 = kc * 32 + l4 * 8;
            int px = pxw + pf * 16 + l15;
            half8v hv;
            #pragma unroll
            for (int j = 0; j < 8; ++j)
                hv[j] = (_Float16)xb[(size_t)(k0 + j) * HW + px];
            bfr[pf][kc] = hv;
        }

    #pragma unroll 1
    for (int ch = 0; ch < 4; ++ch) {
        int ocb = ch * 48;

        half8v afr[3][2];
        #pragma unroll
        for (int nf = 0; nf < 3; ++nf)
            #pragma unroll
            for (int kc = 0; kc < 2; ++kc) {
                int oc = ocb + nf * 16 + l15;
                int k0 = kc * 32 + l4 * 8;
                const float4* wp = (const float4*)&w[oc * 64 + k0];
                float4 wa = wp[0], wb = wp[1];
                half8v a;
                a[0] = (_Float16)wa.x; a[1] = (_Float16)wa.y;
                a[2] = (_Float16)wa.z; a[3] = (_Float16)wa.w;
                a[4] = (_Float16)wb.x; a[5] = (_Float16)wb.y;
                a[6] = (_Float16)wb.z; a[7] = (_Float16)wb.w;
                afr[nf][kc] = a;
            }

        f32x4 acc[3][4];
        #pragma unroll
        for (int nf = 0; nf < 3; ++nf)
            #pragma unroll
            for (int pf = 0; pf < 4; ++pf) acc[nf][pf] = (f32x4)0.f;

        #pragma unroll
        for (int kc = 0; kc < 2; ++kc)
            #pragma unroll
            for (int nf = 0; nf < 3; ++nf)
                #pragma unroll
                for (int pf = 0; pf < 4; ++pf)
                    acc[nf][pf] = __builtin_amdgcn_mfma_f32_16x16x32_f16(
                        afr[nf][kc], bfr[pf][kc], acc[nf][pf], 0, 0, 0);

        __syncthreads();
        #pragma unroll
        for (int nf = 0; nf < 3; ++nf)
            #pragma unroll
            for (int r = 0; r < 4; ++r) {
                int ocl = nf * 16 + l4 * 4 + r;
                float bv = bias[ocb + ocl];
                #pragma unroll
                for (int pf = 0; pf < 4; ++pf)
                    tile[ocl * 264 + wv * 64 + pf * 16 + l15] =
                        f16_bits(acc[nf][pf][r] + bv);
            }
        __syncthreads();

        #pragma unroll
        for (int j = 0; j < 6; ++j) {
            int id = t + 256 * j;
            int row = id >> 5, seg = id & 31;
            uint4 val = *(const uint4*)&tile[row * 264 + seg * 8];
            int oc = ocb + row;
            ushort* dst = qkv + (size_t)(oc >> 6) * BCHW
                        + ((size_t)b * 64 + (oc & 63)) * HW + ppx + seg * 8;
            *(uint4*)dst = val;
        }
    }
}

// ---------------------------------------------------------------------------
// K1.5: transpose v -> vT (f16) (unchanged)
// ---------------------------------------------------------------------------
__global__ __launch_bounds__(256) void vt_kernel(
    const ushort* __restrict__ vbf, ushort* __restrict__ vt)
{
    __shared__ ushort tile[64][66];
    int t = threadIdx.x;
    int bc = blockIdx.x >> 4;
    int tj = blockIdx.x & 15;
    int h0 = (tj >> 2) * 64, w0 = (tj & 3) * 64;
    const ushort* vb = vbf + (size_t)bc * HW;
    ushort* vo = vt + (size_t)bc * HW;
    #pragma unroll
    for (int i = 0; i < 8; ++i) {
        int id = t + 256 * i;
        int r = id >> 5, c2 = id & 31;
        *(uint*)&tile[r][c2 * 2] = *(const uint*)&vb[(h0 + r) * 256 + w0 + c2 * 2];
    }
    __syncthreads();
    #pragma unroll
    for (int i = 0; i < 8; ++i) {
        int id = t + 256 * i;
        int r = id >> 5, c2 = id & 31;
        uint val = (uint)tile[c2 * 2][r] | ((uint)tile[c2 * 2 + 1][r] << 16);
        *(uint*)&vo[(w0 + r) * 256 + h0 + c2 * 2] = val;
    }
}

// ---------------------------------------------------------------------------
// K2 (fused, persistent per-bc): one block per bc, 512 thr / 8 waves,
// loops over 8 h-tiles of 32 rows. K/V fragments register-resident (loaded
// once). Q staged per tile into XOR-swizzled LDS (coalesced). Epilogue
// repacked through LDS for coalesced 16B x/out access.
// ---------------------------------------------------------------------------
#define SST 266                   // sbuf stride for S rows (f32)
#define YST 268                   // y scratch stride (f32)
#define ATS 264                   // attn row stride (f16)
#define SOT 264                   // out-repack stride (f32)

__global__ __launch_bounds__(512, 2) void fused_kernel(
    const ushort* __restrict__ qf, const ushort* __restrict__ kf,
    const ushort* __restrict__ vtf,
    const float* __restrict__ wdw, const float* __restrict__ bdw,
    const float* __restrict__ x, float* __restrict__ out)
{
    __shared__ float sbuf[34 * SST];        // 36.2 KB (S / yL / attn / out overlay)
    __shared__ ushort qlds[48 * 256];       // 24 KB, XOR-swizzled Q tile
    __shared__ float mxf[32];

    int t = threadIdx.x;
    int lane = t & 63, wv = t >> 6;         // 8 waves
    int l15 = lane & 15, l4 = lane >> 4;
    int col = t & 255, half = t >> 8;
    int base = half * 16;

    int bc = blockIdx.x;                    // one block per (b,c)
    int c = bc & 63;

    const ushort* qb = qf  + (size_t)bc * HW;
    const ushort* kb = kf  + (size_t)bc * HW;
    const ushort* vb = vtf + (size_t)bc * HW;
    const float*  xb = x   + (size_t)bc * HW;
    float*        ob = out + (size_t)bc * HW;

    int g0 = wv * 32;

    // ---- preload K and V fragments into registers (once per bc) ----
    half8v ka[2][8], va[2][8];
    {
        const ushort* kr0 = kb + (g0 + l15) * 256 + l4 * 8;
        const ushort* kr1 = kb + (g0 + 16 + l15) * 256 + l4 * 8;
        const ushort* vr0 = vb + (g0 + l15) * 256 + l4 * 8;
        const ushort* vr1 = vb + (g0 + 16 + l15) * 256 + l4 * 8;
        #pragma unroll
        for (int kc = 0; kc < 8; ++kc) {
            ka[0][kc] = *(const half8v*)(kr0 + kc * 32);
            ka[1][kc] = *(const half8v*)(kr1 + kc * 32);
            va[0][kc] = *(const half8v*)(vr0 + kc * 32);
            va[1][kc] = *(const half8v*)(vr1 + kc * 32);
        }
    }

    float w00 = wdw[c*9+0], w01 = wdw[c*9+1], w02 = wdw[c*9+2];
    float w10 = wdw[c*9+3], w11 = wdw[c*9+4], w12 = wdw[c*9+5];
    float w20 = wdw[c*9+6], w21 = wdw[c*9+7], w22 = wdw[c*9+8];
    float bias = bdw[c];

    half8v ones;
    #pragma unroll
    for (int j = 0; j < 8; ++j) ones[j] = (_Float16)1.0f;

    #pragma unroll 1
    for (int tile = 0; tile < 8; ++tile) {
        int h0 = tile * 32;

        // ===== Q stage: 48 rows x 512 B, coalesced, XOR-swizzled placement ==
        #pragma unroll
        for (int s = 0; s < 3; ++s) {
            int id = t + s * 512;           // 0..1535
            int row = id >> 5, cch = id & 31;
            int hq = min(max(h0 - 1 + row, 0), 255);
            uint4 val = *(const uint4*)(qb + hq * 256 + cch * 8);
            *(uint4*)((char*)qlds + row * 512 + ((cch ^ (row & 7)) << 4)) = val;
        }
        __syncthreads();

        // ===== Phase 1: S = Q K^T (Q from swizzled LDS, K from regs) =======
        {
            f32x4 acc[3][2];
            #pragma unroll
            for (int i = 0; i < 3; ++i)
                #pragma unroll
                for (int j = 0; j < 2; ++j) acc[i][j] = (f32x4)0.f;

            #pragma unroll
            for (int kc = 0; kc < 8; ++kc) {
                int ch4 = kc * 4 + l4;
                half8v q0 = *(const half8v*)((char*)qlds + (l15)      * 512 + ((ch4 ^ ( l15       & 7)) << 4));
                half8v q1 = *(const half8v*)((char*)qlds + (16 + l15) * 512 + ((ch4 ^ ((16 + l15) & 7)) << 4));
                half8v q2 = *(const half8v*)((char*)qlds + (32 + l15) * 512 + ((ch4 ^ ((32 + l15) & 7)) << 4));
                __builtin_amdgcn_s_setprio(1);
                acc[0][0] = __builtin_amdgcn_mfma_f32_16x16x32_f16(q0, ka[0][kc], acc[0][0], 0, 0, 0);
                acc[0][1] = __builtin_amdgcn_mfma_f32_16x16x32_f16(q0, ka[1][kc], acc[0][1], 0, 0, 0);
                acc[1][0] = __builtin_amdgcn_mfma_f32_16x16x32_f16(q1, ka[0][kc], acc[1][0], 0, 0, 0);
                acc[1][1] = __builtin_amdgcn_mfma_f32_16x16x32_f16(q1, ka[1][kc], acc[1][1], 0, 0, 0);
                acc[2][0] = __builtin_amdgcn_mfma_f32_16x16x32_f16(q2, ka[0][kc], acc[2][0], 0, 0, 0);
                acc[2][1] = __builtin_amdgcn_mfma_f32_16x16x32_f16(q2, ka[1][kc], acc[2][1], 0, 0, 0);
                __builtin_amdgcn_s_setprio(0);
            }
            #pragma unroll
            for (int hf = 0; hf < 3; ++hf)
                #pragma unroll
                for (int gf = 0; gf < 2; ++gf)
                    #pragma unroll
                    for (int r = 0; r < 4; ++r) {
                        int cr = hf * 16 + l4 * 4 + r;
                        if (cr < 34)
                            sbuf[cr * SST + g0 + gf * 16 + l15] = acc[hf][gf][r];
                    }
        }
        __syncthreads();

        // ===== Phase 2: conv3x3 (LDS rolling window) =====
        float y[16];
        {
            float l0, m0, r0, l1, m1, r1;
            if (base == 0 && h0 == 0) { l0 = m0 = r0 = 0.f; }
            else {
                m0 = sbuf[base * SST + col];
                l0 = (col > 0)   ? sbuf[base * SST + col - 1] : 0.f;
                r0 = (col < 255) ? sbuf[base * SST + col + 1] : 0.f;
            }
            m1 = sbuf[(base + 1) * SST + col];
            l1 = (col > 0)   ? sbuf[(base + 1) * SST + col - 1] : 0.f;
            r1 = (col < 255) ? sbuf[(base + 1) * SST + col + 1] : 0.f;

            #pragma unroll
            for (int i = 0; i < 16; ++i) {
                float l2, m2, r2;
                if (h0 + base + i + 1 < 256) {
                    int sl = (base + i + 2) * SST;
                    m2 = sbuf[sl + col];
                    l2 = (col > 0)   ? sbuf[sl + col - 1] : 0.f;
                    r2 = (col < 255) ? sbuf[sl + col + 1] : 0.f;
                } else { l2 = m2 = r2 = 0.f; }
                y[i] = bias
                     + w00*l0 + w01*m0 + w02*r0
                     + w10*l1 + w11*m1 + w12*r1
                     + w20*l2 + w21*m2 + w22*r2;
                l0 = l1; m0 = m1; r0 = r1;
                l1 = l2; m1 = m2; r1 = r2;
            }
        }
        __syncthreads();                   // conv reads of sbuf done

        // ===== Phase 3a: row max via LDS transpose =====
        float* yL = sbuf;
        #pragma unroll
        for (int i = 0; i < 16; ++i)
            yL[(base + i) * YST + col] = y[i];
        __syncthreads();

        {
            int r = t >> 4, c16 = t & 15;
            const f32x4* p = (const f32x4*)&yL[r * YST + c16 * 16];
            f32x4 v0 = p[0], v1 = p[1], v2 = p[2], v3 = p[3];
            float m = v0[0];
            #pragma unroll
            for (int j = 1; j < 4; ++j) m = fmaxf(m, v0[j]);
            #pragma unroll
            for (int j = 0; j < 4; ++j) m = fmaxf(m, v1[j]);
            #pragma unroll
            for (int j = 0; j < 4; ++j) m = fmaxf(m, v2[j]);
            #pragma unroll
            for (int j = 0; j < 4; ++j) m = fmaxf(m, v3[j]);
            m = fmaxf(m, __shfl_xor(m, 1));
            m = fmaxf(m, __shfl_xor(m, 2));
            m = fmaxf(m, __shfl_xor(m, 4));
            m = fmaxf(m, __shfl_xor(m, 8));
            if (c16 == 0) mxf[r] = m;
        }
        __syncthreads();

        // ===== Phase 3b: exp -> f16 attn =====
        ushort* attnb = (ushort*)sbuf;
        #pragma unroll
        for (int i = 0; i < 16; ++i) {
            float e = __expf(y[i] - mxf[base + i]);
            attnb[(base + i) * ATS + col] = f16_bits(e);
        }
        __syncthreads();

        // ===== Phase 4: PV + ones-sum (attn from LDS, V from regs) =====
        f32x4 pacc[2][2], accs[2];
        #pragma unroll
        for (int i = 0; i < 2; ++i) {
            accs[i] = (f32x4)0.f;
            #pragma unroll
            for (int j = 0; j < 2; ++j) pacc[i][j] = (f32x4)0.f;
        }

        #pragma unroll
        for (int kc = 0; kc < 8; ++kc) {
            half8v af0 = *(const half8v*)&attnb[l15 * ATS + kc * 32 + l4 * 8];
            half8v af1 = *(const half8v*)&attnb[(16 + l15) * ATS + kc * 32 + l4 * 8];
            __builtin_amdgcn_s_setprio(1);
            pacc[0][0] = __builtin_amdgcn_mfma_f32_16x16x32_f16(af0, va[0][kc], pacc[0][0], 0, 0, 0);
            pacc[0][1] = __builtin_amdgcn_mfma_f32_16x16x32_f16(af0, va[1][kc], pacc[0][1], 0, 0, 0);
            accs[0]    = __builtin_amdgcn_mfma_f32_16x16x32_f16(af0, ones, accs[0], 0, 0, 0);
            pacc[1][0] = __builtin_amdgcn_mfma_f32_16x16x32_f16(af1, va[0][kc], pacc[1][0], 0, 0, 0);
            pacc[1][1] = __builtin_amdgcn_mfma_f32_16x16x32_f16(af1, va[1][kc], pacc[1][1], 0, 0, 0);
            accs[1]    = __builtin_amdgcn_mfma_f32_16x16x32_f16(af1, ones, accs[1], 0, 0, 0);
            __builtin_amdgcn_s_setprio(0);
        }
        __syncthreads();                   // attn reads done before overlay

        // ===== repack normalized output into LDS =====
        float* og = sbuf;                  // [32][SOT]
        #pragma unroll
        for (int hf = 0; hf < 2; ++hf)
            #pragma unroll
            for (int r = 0; r < 4; ++r) {
                int row = hf * 16 + l4 * 4 + r;
                float inv = 1.0f / accs[hf][r];
                #pragma unroll
                for (int wf = 0; wf < 2; ++wf)
                    og[row * SOT + g0 + wf * 16 + l15] = pacc[hf][wf][r] * inv;
            }
        __syncthreads();

        // ===== coalesced out pass: +x residual, 16B stores =====
        #pragma unroll
        for (int s = 0; s < 4; ++s) {
            int id = t + s * 512;          // 0..2047
            int row = id >> 6, seg = id & 63;
            f32x4 v = *(const f32x4*)&og[row * SOT + seg * 4];
            f32x4 xr = *(const f32x4*)&xb[(h0 + row) * 256 + seg * 4];
            v += xr;
            *(f32x4*)&ob[(h0 + row) * 256 + seg * 4] = v;
        }
        // no barrier needed here: next tile's Q-stage touches qlds only;
        // sbuf is rewritten only after the next __syncthreads()
    }
}

// ---------------------------------------------------------------------------
extern "C" void kernel_launch(void* const* d_in, const int* in_sizes, int n_in,
                              void* d_out, int out_size, void* d_ws, size_t ws_size,
                              hipStream_t stream)
{
    const float* x     = (const float*)d_in[0];
    const float* w_qkv = (const float*)d_in[1];
    const float* b_qkv = (const float*)d_in[2];
    const float* w_dw  = (const float*)d_in[3];
    const float* b_dw  = (const float*)d_in[4];

    ushort* qf  = (ushort*)d_ws;                 // q plane
    ushort* kf  = qf + (size_t)BCHW;             // k plane
    ushort* vf  = kf + (size_t)BCHW;             // v plane
    ushort* vtp = vf + (size_t)BCHW;             // vT plane
    float*  out = (float*)d_out;

    qkv_kernel  <<<B * HW / 256, 256, 0, stream>>>(x, w_qkv, b_qkv, qf);
    vt_kernel   <<<B * C * 16,   256, 0, stream>>>(vf, vtp);
    fused_kernel<<<B * C,        512, 0, stream>>>(qf, kf, vtp, w_dw, b_dw, x, out);
}